// Round 15
// baseline (1674.975 us; speedup 1.0000x reference)
//
#include <hip/hip_runtime.h>
#include <math.h>

// ---------- types / helpers ----------
typedef unsigned short u16;
typedef short short8 __attribute__((ext_vector_type(8)));
typedef float f32x4 __attribute__((ext_vector_type(4)));

#define DEV static __device__ __forceinline__

DEV float bf2f(u16 h) { union { unsigned int u; float f; } v; v.u = ((unsigned int)h) << 16; return v.f; }
DEV u16 f2bf(float f) {
  union { float f; unsigned int u; } v; v.f = f;
  unsigned int r = v.u + 0x7FFFu + ((v.u >> 16) & 1u);  // RNE
  return (u16)(r >> 16);
}

DEV void gl_lds16(const void* g, void* l) {
  __builtin_amdgcn_global_load_lds(
      (const __attribute__((address_space(1))) unsigned int*)g,
      (__attribute__((address_space(3))) unsigned int*)l, 16, 0, 0);
}

template <int N> DEV void vm_wait() {
  if constexpr (N == 0) asm volatile("s_waitcnt vmcnt(0)" ::: "memory");
  else if constexpr (N == 6) asm volatile("s_waitcnt vmcnt(6)" ::: "memory");
  else if constexpr (N == 8) asm volatile("s_waitcnt vmcnt(8)" ::: "memory");
  else static_assert(N == 0 || N == 6 || N == 8, "add literal");
}

DEV void lgkm0_pin() {
  asm volatile("s_waitcnt lgkmcnt(0)" ::: "memory");
  __builtin_amdgcn_sched_barrier(0);
}

// XCD-aware block swizzle. gx%8==0: each XCD owns a bx-chunk (x all by).
// else: each XCD owns a contiguous swz-chunk (by-major). Both bijective
// (all grids used have nwg%8==0).
DEV void xcd_swizzle(int& bx, int& by) {
  int gx = gridDim.x, gy = gridDim.y;
  int lin = by * gx + bx;
  int xcd = lin & 7, i = lin >> 3;
  if ((gx & 7) == 0) {
    int cx = gx >> 3;
    bx = xcd * cx + i % cx;
    by = i / cx;
  } else {
    int cpx = (gx * gy) >> 3;
    int swz = xcd * cpx + i;
    bx = swz % gx;
    by = swz / gx;
  }
}

// ---------- RMSNorm: f32 [2048][4096] -> bf16 (optionally split hi/lo) ----------
template <bool SPLIT>
__global__ __launch_bounds__(256) void rmsnorm_kernel(
    const float* __restrict__ x, const float* __restrict__ g,
    u16* __restrict__ oh, u16* __restrict__ ol) {
  int row = blockIdx.x, t = threadIdx.x;
  const float* xr = x + (size_t)row * 4096;
  float4 vals[4];
  float s = 0.f;
#pragma unroll
  for (int i = 0; i < 4; i++) {
    vals[i] = ((const float4*)xr)[t + i * 256];
    s += vals[i].x * vals[i].x + vals[i].y * vals[i].y + vals[i].z * vals[i].z + vals[i].w * vals[i].w;
  }
#pragma unroll
  for (int m = 1; m < 64; m <<= 1) s += __shfl_xor(s, m);
  __shared__ float red[4];
  if ((t & 63) == 0) red[t >> 6] = s;
  __syncthreads();
  s = red[0] + red[1] + red[2] + red[3];
  float rinv = rsqrtf(s * (1.f / 4096.f) + 1.1920929e-07f);
#pragma unroll
  for (int i = 0; i < 4; i++) {
    float4 gv = ((const float4*)g)[t + i * 256];
    float4 v = vals[i];
    float f[4] = {v.x * rinv * gv.x, v.y * rinv * gv.y, v.z * rinv * gv.z, v.w * rinv * gv.w};
    ushort4 rh, rl;
    u16* hp = (u16*)&rh; u16* lp = (u16*)&rl;
#pragma unroll
    for (int j = 0; j < 4; j++) {
      u16 hi = f2bf(f[j]);
      hp[j] = hi;
      if (SPLIT) lp[j] = f2bf(f[j] - bf2f(hi));
    }
    ((ushort4*)(oh + (size_t)row * 4096))[t + i * 256] = rh;
    if (SPLIT) ((ushort4*)(ol + (size_t)row * 4096))[t + i * 256] = rl;
  }
}

// ---------- transpose-convert, 64x64 tiles: w f32 [K][N] -> wT bf16 [N][K] ----------
// float2 reads (256B/row), ushort2 writes (128B segments). Block (32,8).
__global__ void tconv_kernel(const float* __restrict__ in, u16* __restrict__ out, int K, int N) {
  __shared__ float tile[64][65];
  int k0 = blockIdx.y * 64, n0 = blockIdx.x * 64;
  int tx = threadIdx.x, ty = threadIdx.y;
#pragma unroll
  for (int i = 0; i < 8; i++) {
    int r = ty + 8 * i;
    float2 v = *(const float2*)&in[(size_t)(k0 + r) * N + n0 + tx * 2];
    tile[r][tx * 2] = v.x;
    tile[r][tx * 2 + 1] = v.y;
  }
  __syncthreads();
#pragma unroll
  for (int i = 0; i < 8; i++) {
    int c = ty + 8 * i;
    ushort2 o;
    o.x = f2bf(tile[tx * 2][c]);
    o.y = f2bf(tile[tx * 2 + 1][c]);
    *(ushort2*)&out[(size_t)(n0 + c) * K + k0 + tx * 2] = o;
  }
}

// ---------- 64x64 transpose-convert, 128-col interleave (for [w1|w3] packing) ----------
// out row = (n/128)*256 + n%128 + off. 64-col tiles never straddle a 128-group.
__global__ void tconv_ilv_kernel(const float* __restrict__ in, u16* __restrict__ out,
                                 int K, int N, int off) {
  __shared__ float tile[64][65];
  int k0 = blockIdx.y * 64, n0 = blockIdx.x * 64;
  int tx = threadIdx.x, ty = threadIdx.y;
#pragma unroll
  for (int i = 0; i < 8; i++) {
    int r = ty + 8 * i;
    float2 v = *(const float2*)&in[(size_t)(k0 + r) * N + n0 + tx * 2];
    tile[r][tx * 2] = v.x;
    tile[r][tx * 2 + 1] = v.y;
  }
  __syncthreads();
#pragma unroll
  for (int i = 0; i < 8; i++) {
    int c = ty + 8 * i;
    int n = n0 + c;
    int orow = ((n >> 7) << 8) + (n & 127) + off;
    ushort2 o;
    o.x = f2bf(tile[tx * 2][c]);
    o.y = f2bf(tile[tx * 2 + 1][c]);
    *(ushort2*)&out[(size_t)orow * K + k0 + tx * 2] = o;
  }
}

// ---------- 64x64 transpose-convert split: w f32 [K][N] -> hi/lo bf16 [N][K] ----------
__global__ void tconv_split_kernel(const float* __restrict__ in, u16* __restrict__ oh,
                                   u16* __restrict__ ol, int K, int N) {
  __shared__ float tile[64][65];
  int k0 = blockIdx.y * 64, n0 = blockIdx.x * 64;
  int tx = threadIdx.x, ty = threadIdx.y;
#pragma unroll
  for (int i = 0; i < 8; i++) {
    int r = ty + 8 * i;
    float2 v = *(const float2*)&in[(size_t)(k0 + r) * N + n0 + tx * 2];
    tile[r][tx * 2] = v.x;
    tile[r][tx * 2 + 1] = v.y;
  }
  __syncthreads();
#pragma unroll
  for (int i = 0; i < 8; i++) {
    int c = ty + 8 * i;
    float f0 = tile[tx * 2][c], f1 = tile[tx * 2 + 1][c];
    u16 h0 = f2bf(f0), h1 = f2bf(f1);
    ushort2 vh, vl;
    vh.x = h0; vh.y = h1;
    vl.x = f2bf(f0 - bf2f(h0)); vl.y = f2bf(f1 - bf2f(h1));
    size_t idx = (size_t)(n0 + c) * K + k0 + tx * 2;
    *(ushort2*)&oh[idx] = vh;
    *(ushort2*)&ol[idx] = vl;
  }
}

// ---------- RoPE cos/sin table (double precision): tab[s][j] = {cos,sin} ----------
__global__ __launch_bounds__(256) void rope_table_kernel(float* __restrict__ tab) {
  int i = blockIdx.x * 256 + threadIdx.x;  // 2048*64
  int j = i & 63, s = i >> 6;
  double freq = pow(10000.0, -(double)j / 64.0);
  double ang = (double)s * freq;
  tab[i * 2] = (float)cos(ang);
  tab[i * 2 + 1] = (float)sin(ang);
}

// ---------- RoPE in place on (hi,lo) [2048][8192]; one wave owns one 128-col slot ----------
__global__ __launch_bounds__(256) void rope_inplace_kernel(
    u16* hi, u16* lo, const float* __restrict__ tab) {
  int idx = blockIdx.x * 256 + threadIdx.x;  // (s, slot6, j)
  int j = idx & 63, hd = (idx >> 6) & 63, s = idx >> 12;
  size_t base = (size_t)s * 8192 + hd * 128;
  float xe = bf2f(hi[base + 2 * j]) + bf2f(lo[base + 2 * j]);
  float xo = bf2f(hi[base + 2 * j + 1]) + bf2f(lo[base + 2 * j + 1]);
  float cs = tab[(s * 64 + j) * 2], sn = tab[(s * 64 + j) * 2 + 1];
  float r0 = xe * cs - xo * sn;
  float r1 = xe * sn + xo * cs;
  u16 h0 = f2bf(r0), h1 = f2bf(r1);
  hi[base + j] = h0;      lo[base + j] = f2bf(r0 - bf2f(h0));
  hi[base + 64 + j] = h1; lo[base + 64 + j] = f2bf(r1 - bf2f(h1));
}

// ---------- 8-phase 256x256 GEMM, 2-tiles-ahead staging (round-5 proven) ----------
// A bf16 [M][lda] @ Bt bf16 [N][ldb] -> C [M][N]. 512 thr = 8 waves (2M x 4N).
// TRIK: K' = 3*Kseg, per-segment operand select: seg0 A*B, seg1 A2*B, seg2 A*B2.
// OUT=3: fused-silu epilogue for interleaved [w1|w3] B.
template <int OUT, bool TRIK>  // OUT: 0=f32, 1=bf16, 2=split hi/lo, 3=fused silu
__global__ __launch_bounds__(512, 2) void gemm8_kernel(
    const u16* __restrict__ A, const u16* __restrict__ A2,
    const u16* __restrict__ B, const u16* __restrict__ B2,
    void* __restrict__ C, u16* __restrict__ C2,
    int M, int N, int K, int lda, int ldb) {
  __shared__ __attribute__((aligned(16))) u16 SMEM[65536];  // 128KB: A 64KB | B 64KB
  int t = threadIdx.x, l = t & 63, w = t >> 6;
  int bx = blockIdx.x, by = blockIdx.y;
  xcd_swizzle(bx, by);
  int m0 = by * 256, n0 = bx * 256;
  int wm = w >> 2, wn = w & 3, bh = wn >> 1;
  f32x4 acc[8][4] = {};
  int nk = K >> 6;

  auto AsP = [&](int d, int h) -> u16* { return SMEM + (d * 2 + h) * 8192; };
  auto BsP = [&](int d, int h) -> u16* { return SMEM + 32768 + (d * 2 + h) * 8192; };

  auto stageA = [&](int kt, int dd) {
    const u16* Ab = A; int kc = kt << 6;
    if (TRIK) { int seg = kt >> 6; Ab = (seg == 1) ? A2 : A; kc = (kt & 63) << 6; }
#pragma unroll
    for (int i = 0; i < 4; i++) {
      int id = i * 512 + t;
      int hh = id >> 10, idc = id & 1023;
      int r = idc >> 3, cb = idc & 7;
      int csw = ((cb * 16) ^ ((r & 7) << 4)) >> 1;
      gl_lds16(&Ab[(size_t)(m0 + hh * 128 + r) * lda + kc + csw], AsP(dd, hh) + idc * 8);
    }
  };
  auto stageB = [&](int kt, int dd) {
    const u16* Bb = B; int kc = kt << 6;
    if (TRIK) { int seg = kt >> 6; Bb = (seg == 2) ? B2 : B; kc = (kt & 63) << 6; }
#pragma unroll
    for (int i = 0; i < 4; i++) {
      int id = i * 512 + t;
      int hh = id >> 10, idc = id & 1023;
      int r = idc >> 3, cb = idc & 7;
      int csw = ((cb * 16) ^ ((r & 7) << 4)) >> 1;
      gl_lds16(&Bb[(size_t)(n0 + hh * 128 + r) * ldb + kc + csw], BsP(dd, hh) + idc * 8);
    }
  };

  int lq = l >> 4, lr = l & 15;
  short8 af[4][2], bf[4][2];
  auto rdA = [&](int d, int mh) {
    const char* Ax = (const char*)AsP(d, wm);
#pragma unroll
    for (int m = 0; m < 4; m++) {
      int r = mh * 64 + m * 16 + lr;
      int rb = r * 128, rx = (r & 7) << 4;
#pragma unroll
      for (int kh = 0; kh < 2; kh++)
        af[m][kh] = *(const short8*)(Ax + rb + ((kh * 64 + lq * 16) ^ rx));
    }
  };
  auto rdB2 = [&](int d, int nlo, int nhi) {
    const char* Bx = (const char*)BsP(d, bh);
#pragma unroll
    for (int n = 0; n < 4; n++) {
      if (n < nlo || n >= nhi) continue;
      int r = (wn & 1) * 64 + n * 16 + lr;
      int rb = r * 128, rx = (r & 7) << 4;
#pragma unroll
      for (int kh = 0; kh < 2; kh++)
        bf[n][kh] = *(const short8*)(Bx + rb + ((kh * 64 + lq * 16) ^ rx));
    }
  };
  auto mm8 = [&](int mo, int no) {
    __builtin_amdgcn_s_setprio(1);
#pragma unroll
    for (int m = 0; m < 4; m++)
#pragma unroll
      for (int n = 0; n < 2; n++)
#pragma unroll
        for (int kh = 0; kh < 2; kh++)
          acc[mo + m][no + n] =
              __builtin_amdgcn_mfma_f32_16x16x32_bf16(af[m][kh], bf[no + n][kh], acc[mo + m][no + n], 0, 0, 0);
    __builtin_amdgcn_s_setprio(0);
  };

  stageB(0, 0); stageA(0, 0);
  stageB(1, 1); stageA(1, 1);
  vm_wait<8>();
  __builtin_amdgcn_s_barrier();

  for (int kt = 0; kt < nk; ++kt) {
    int d = kt & 1;
    rdA(d, 0);
    rdB2(d, 0, 2);
    __builtin_amdgcn_s_barrier();
    lgkm0_pin();
    mm8(0, 0);
    __builtin_amdgcn_s_barrier();
    rdB2(d, 2, 4);
    __builtin_amdgcn_s_barrier();
    lgkm0_pin();
    mm8(0, 2);
    __builtin_amdgcn_s_barrier();
    rdA(d, 1);
    if (kt + 2 < nk) stageB(kt + 2, d);
    __builtin_amdgcn_s_barrier();
    lgkm0_pin();
    mm8(4, 2);
    __builtin_amdgcn_s_barrier();
    if (kt + 2 < nk) stageA(kt + 2, d);
    __builtin_amdgcn_s_barrier();
    mm8(4, 0);
    if (kt + 2 < nk) vm_wait<8>();
    else vm_wait<0>();
    __builtin_amdgcn_s_barrier();
  }

  if (OUT == 3) {
    __syncthreads();
    float* EPI = (float*)SMEM;  // 256 x 128 f32 = 128KB
    if (wn >= 2) {
#pragma unroll
      for (int m = 0; m < 8; m++)
#pragma unroll
        for (int i = 0; i < 4; i++) {
          int rl = wm * 128 + m * 16 + lq * 4 + i;
#pragma unroll
          for (int n = 0; n < 4; n++)
            EPI[rl * 128 + (wn - 2) * 64 + n * 16 + lr] = acc[m][n][i];
        }
    }
    __syncthreads();
    if (wn < 2) {
      u16* Ob = (u16*)C;
      int cb = n0 >> 1;
#pragma unroll
      for (int m = 0; m < 8; m++)
#pragma unroll
        for (int i = 0; i < 4; i++) {
          int rl = wm * 128 + m * 16 + lq * 4 + i;
          int row = m0 + rl;
#pragma unroll
          for (int n = 0; n < 4; n++) {
            float a = acc[m][n][i];
            float b = EPI[rl * 128 + wn * 64 + n * 16 + lr];
            float r = a * (b / (1.f + expf(-b)));
            Ob[(size_t)row * N + cb + wn * 64 + n * 16 + lr] = f2bf(r);
          }
        }
    }
    return;
  }

#pragma unroll
  for (int m = 0; m < 8; m++) {
#pragma unroll
    for (int i = 0; i < 4; i++) {
      int row = m0 + wm * 128 + m * 16 + lq * 4 + i;
      size_t rb = (size_t)row * N + n0 + wn * 64 + lr;
#pragma unroll
      for (int n = 0; n < 4; n++) {
        float f = acc[m][n][i];
        if (OUT == 0) ((float*)C)[rb + n * 16] = f;
        else if (OUT == 1) ((u16*)C)[rb + n * 16] = f2bf(f);
        else {
          u16 hi = f2bf(f);
          ((u16*)C)[rb + n * 16] = hi;
          C2[rb + n * 16] = f2bf(f - bf2f(hi));
        }
      }
    }
  }
}

// ---------- 2-phase 128x256 GEMM (round-5 proven; N=4096 shapes) ----------
// OUT: 0=f32, 1=bf16, 2=bf16 transposed [N][M].
template <int OUT>
__global__ __launch_bounds__(512, 2) void gemm8n_kernel(
    const u16* __restrict__ A, const u16* __restrict__ B, void* __restrict__ C,
    int M, int N, int K, int lda, int ldb) {
  __shared__ __attribute__((aligned(16))) u16 As[2][128 * 64];
  __shared__ __attribute__((aligned(16))) u16 Bs3[3][256 * 64];
  int t = threadIdx.x, l = t & 63, w = t >> 6;
  int bx = blockIdx.x, by = blockIdx.y;
  xcd_swizzle(bx, by);
  int m0 = by * 128, n0 = bx * 256;
  int wm = w >> 2, wn = w & 3;
  f32x4 acc[4][4] = {};
  int nk = K >> 6;

  auto stageA = [&](int kt, int dd) {  // 2 loads/thread
    int kc = kt << 6;
#pragma unroll
    for (int i = 0; i < 2; i++) {
      int id = i * 512 + t;
      int r = id >> 3, cb = id & 7;
      int csw = ((cb * 16) ^ ((r & 7) << 4)) >> 1;
      gl_lds16(&A[(size_t)(m0 + r) * lda + kc + csw], &As[dd][id * 8]);
    }
  };
  auto stageB = [&](int kt, int bb) {  // 4 loads/thread
    int kc = kt << 6;
#pragma unroll
    for (int i = 0; i < 4; i++) {
      int id = i * 512 + t;
      int r = id >> 3, cb = id & 7;
      int csw = ((cb * 16) ^ ((r & 7) << 4)) >> 1;
      gl_lds16(&B[(size_t)(n0 + r) * ldb + kc + csw], &Bs3[bb][id * 8]);
    }
  };

  int lq = l >> 4, lr = l & 15;
  short8 af0[4], af1[4], bf0[4], bf1[4];
  auto rdA4 = [&](short8 (&dst)[4], int d, int kh) {
    const char* Ax = (const char*)As[d];
#pragma unroll
    for (int m = 0; m < 4; m++) {
      int r = wm * 64 + m * 16 + lr;
      dst[m] = *(const short8*)(Ax + r * 128 + ((kh * 64 + lq * 16) ^ ((r & 7) << 4)));
    }
  };
  auto rdB4 = [&](short8 (&dst)[4], int bb, int kh) {
    const char* Bx = (const char*)Bs3[bb];
#pragma unroll
    for (int n = 0; n < 4; n++) {
      int r = wn * 64 + n * 16 + lr;
      dst[n] = *(const short8*)(Bx + r * 128 + ((kh * 64 + lq * 16) ^ ((r & 7) << 4)));
    }
  };
  auto mm16 = [&](short8 (&a)[4], short8 (&b)[4]) {
    __builtin_amdgcn_s_setprio(1);
#pragma unroll
    for (int m = 0; m < 4; m++)
#pragma unroll
      for (int n = 0; n < 4; n++)
        acc[m][n] = __builtin_amdgcn_mfma_f32_16x16x32_bf16(a[m], b[n], acc[m][n], 0, 0, 0);
    __builtin_amdgcn_s_setprio(0);
  };

  // prologue
  stageB(0, 0); stageA(0, 0);
  stageB(1, 1); stageA(1, 1);
  vm_wait<6>();
  __builtin_amdgcn_s_barrier();

  for (int kt = 0; kt < nk; ++kt) {
    int d = kt & 1;
    int bb = kt % 3, bb2 = (kt + 2) % 3;
    // P1: stage (t+2).B; read kh0 frags; MFMA kh0
    if (kt + 2 < nk) stageB(kt + 2, bb2);
    rdA4(af0, d, 0); rdB4(bf0, bb, 0);
    __builtin_amdgcn_s_barrier();
    lgkm0_pin();
    mm16(af0, bf0);
    __builtin_amdgcn_s_barrier();
    // P2: read kh1 frags; lgkm0; bar; stage (t+2).A; vmcnt(6); MFMA kh1
    rdA4(af1, d, 1); rdB4(bf1, bb, 1);
    lgkm0_pin();
    __builtin_amdgcn_s_barrier();
    if (kt + 2 < nk) { stageA(kt + 2, d); vm_wait<6>(); }
    else vm_wait<0>();
    mm16(af1, bf1);
    __builtin_amdgcn_s_barrier();
  }
  // epilogue
  if (OUT == 2) {
    u16* Cb = (u16*)C;
#pragma unroll
    for (int m = 0; m < 4; m++) {
      int sbase = m0 + wm * 64 + m * 16 + lq * 4;
#pragma unroll
      for (int n = 0; n < 4; n++) {
        int dg = n0 + wn * 64 + n * 16 + lr;
        ushort4 pk;
        pk.x = f2bf(acc[m][n][0]); pk.y = f2bf(acc[m][n][1]);
        pk.z = f2bf(acc[m][n][2]); pk.w = f2bf(acc[m][n][3]);
        *(ushort4*)&Cb[(size_t)dg * M + sbase] = pk;
      }
    }
    return;
  }
#pragma unroll
  for (int m = 0; m < 4; m++) {
#pragma unroll
    for (int i = 0; i < 4; i++) {
      int row = m0 + wm * 64 + m * 16 + lq * 4 + i;
      size_t rb = (size_t)row * N + n0 + wn * 64 + lr;
#pragma unroll
      for (int n = 0; n < 4; n++) {
        float f = acc[m][n][i];
        if (OUT == 0) ((float*)C)[rb + n * 16] = f;
        else ((u16*)C)[rb + n * 16] = f2bf(f);
      }
    }
  }
}

// ---------- flash attention (no scale, no mask), split-precision QK^T ----------
// QBLK=128 via 4 waves x 2 q-groups (32 q-rows per wave against the same staged
// K/V tile): halves block-level K/V staging vs QBLK=64, keeps 256 threads and
// 2 blocks/CU (LDS 66KB). Per-output math identical to the proven kernel.
__global__ __launch_bounds__(256, 2) void attn_kernel(
    const u16* __restrict__ qh, const u16* __restrict__ ql,
    const u16* __restrict__ kh, const u16* __restrict__ kl,
    const u16* __restrict__ vt, u16* __restrict__ out) {
  const int QS = 8192;
  __shared__ __attribute__((aligned(16))) u16 KH[64 * 128];   // [kv][d], XOR-swizzled
  __shared__ __attribute__((aligned(16))) u16 KL[64 * 128];
  __shared__ __attribute__((aligned(16))) u16 Vl[128 * 64];   // [d][kv], XOR-swizzled
  __shared__ __attribute__((aligned(16))) u16 Pl[8][16 * 72]; // per (wave,group) [q][kv]
  int t = threadIdx.x, l = t & 63, w = t >> 6;
  int hd = blockIdx.y, q0 = blockIdx.x * 128;
  int lr = l & 15, lq = l >> 4;
  int qrow0 = q0 + (w * 2) * 16 + lr;
  int qrow1 = q0 + (w * 2 + 1) * 16 + lr;
  short8 qfh[2][4], qfl[2][4];
#pragma unroll
  for (int g = 0; g < 2; g++) {
    size_t qoff = (size_t)(g ? qrow1 : qrow0) * QS + hd * 128 + lq * 8;
#pragma unroll
    for (int kc = 0; kc < 4; kc++) {
      qfh[g][kc] = *(const short8*)&qh[qoff + kc * 32];
      qfl[g][kc] = *(const short8*)&ql[qoff + kc * 32];
    }
  }
  f32x4 accO[2][8] = {};
  float mrun[2] = {-__builtin_inff(), -__builtin_inff()};
  float lrun[2] = {0.f, 0.f};
  for (int kv0 = 0; kv0 < 2048; kv0 += 64) {
    // stage K hi/lo [64][128] + V^T [128][64]; swizzled source, linear dest
#pragma unroll
    for (int i = 0; i < 4; i++) {
      int ci = i * 256 + t;
      int row = ci >> 4;
      int cb = (ci & 15) ^ (row & 7);
      size_t src = (size_t)(kv0 + row) * QS + hd * 128 + cb * 8;
      gl_lds16(&kh[src], &KH[ci * 8]);
      gl_lds16(&kl[src], &KL[ci * 8]);
    }
#pragma unroll
    for (int i = 0; i < 4; i++) {
      int ci = i * 256 + t;
      int row = ci >> 3;
      int cb = (ci & 7) ^ (row & 7);
      gl_lds16(&vt[((size_t)hd * 128 + row) * 2048 + kv0 + cb * 8], &Vl[ci * 8]);
    }
    __syncthreads();
#pragma unroll
    for (int g = 0; g < 2; g++) {
      // S^T = K @ Q^T with 3-product split
      f32x4 accS[4];
#pragma unroll
      for (int mm = 0; mm < 4; mm++) {
        accS[mm] = (f32x4){0.f, 0.f, 0.f, 0.f};
#pragma unroll
        for (int kc = 0; kc < 4; kc++) {
          int rowk = mm * 16 + lr;
          int logb = rowk * 256 + kc * 64 + lq * 16;
          int phys = logb ^ ((rowk & 7) << 4);
          short8 a_h = *(const short8*)((const char*)KH + phys);
          short8 a_l = *(const short8*)((const char*)KL + phys);
          accS[mm] = __builtin_amdgcn_mfma_f32_16x16x32_bf16(a_h, qfh[g][kc], accS[mm], 0, 0, 0);
          accS[mm] = __builtin_amdgcn_mfma_f32_16x16x32_bf16(a_h, qfl[g][kc], accS[mm], 0, 0, 0);
          accS[mm] = __builtin_amdgcn_mfma_f32_16x16x32_bf16(a_l, qfh[g][kc], accS[mm], 0, 0, 0);
        }
      }
      // online softmax; lane owns q-row lr, kv spread over {l^16,l^32}
      float tmax = -__builtin_inff();
#pragma unroll
      for (int mm = 0; mm < 4; mm++)
        tmax = fmaxf(tmax, fmaxf(fmaxf(accS[mm][0], accS[mm][1]), fmaxf(accS[mm][2], accS[mm][3])));
      tmax = fmaxf(tmax, __shfl_xor(tmax, 16));
      tmax = fmaxf(tmax, __shfl_xor(tmax, 32));
      float mnew = fmaxf(mrun[g], tmax);
      float scale = expf(mrun[g] - mnew);
      float psum = 0.f;
      u16* Pw = &Pl[w * 2 + g][0];
#pragma unroll
      for (int mm = 0; mm < 4; mm++) {
        float p0 = expf(accS[mm][0] - mnew), p1 = expf(accS[mm][1] - mnew);
        float p2 = expf(accS[mm][2] - mnew), p3 = expf(accS[mm][3] - mnew);
        psum += (p0 + p1) + (p2 + p3);
        ushort4 pk;
        pk.x = f2bf(p0); pk.y = f2bf(p1); pk.z = f2bf(p2); pk.w = f2bf(p3);
        *(ushort4*)&Pw[lr * 72 + mm * 16 + lq * 4] = pk;
      }
      psum += __shfl_xor(psum, 16);
      psum += __shfl_xor(psum, 32);
      lrun[g] = lrun[g] * scale + psum;
      mrun[g] = mnew;
#pragma unroll
      for (int mm = 0; mm < 8; mm++) accO[g][mm] = accO[g][mm] * scale;
      // O^T += V^T @ P^T
#pragma unroll
      for (int kc2 = 0; kc2 < 2; kc2++) {
        short8 bp = *(const short8*)((const char*)Pw + lr * 144 + kc2 * 64 + lq * 16);
#pragma unroll
        for (int mm = 0; mm < 8; mm++) {
          int rowd = mm * 16 + lr;
          int logb = rowd * 128 + kc2 * 64 + lq * 16;
          int phys = logb ^ ((rowd & 7) << 4);
          short8 av = *(const short8*)((const char*)Vl + phys);
          accO[g][mm] = __builtin_amdgcn_mfma_f32_16x16x32_bf16(av, bp, accO[g][mm], 0, 0, 0);
        }
      }
    }
    __syncthreads();
  }
#pragma unroll
  for (int g = 0; g < 2; g++) {
    float rinv = 1.f / lrun[g];
    int qrow = g ? qrow1 : qrow0;
#pragma unroll
    for (int mm = 0; mm < 8; mm++) {
      ushort4 pk;
      pk.x = f2bf(accO[g][mm][0] * rinv); pk.y = f2bf(accO[g][mm][1] * rinv);
      pk.z = f2bf(accO[g][mm][2] * rinv); pk.w = f2bf(accO[g][mm][3] * rinv);
      *(ushort4*)&out[(size_t)qrow * 4096 + hd * 128 + mm * 16 + lq * 4] = pk;
    }
  }
}

// ---------- launch ----------
extern "C" void kernel_launch(void* const* d_in, const int* in_sizes, int n_in,
                              void* d_out, int out_size, void* d_ws, size_t ws_size,
                              hipStream_t stream) {
  const float* x      = (const float*)d_in[0];
  const float* wq     = (const float*)d_in[1];
  const float* wk     = (const float*)d_in[2];
  const float* wv     = (const float*)d_in[3];
  const float* wo     = (const float*)d_in[4];
  const float* w1     = (const float*)d_in[5];
  const float* w2     = (const float*)d_in[6];
  const float* w3     = (const float*)d_in[7];
  const float* g_attn = (const float*)d_in[8];
  const float* g_ffn  = (const float*)d_in[9];

  char* ws = (char*)d_ws;
  // region layout (total ~383 MB)
  char* R0 = ws;                                   // 180.4MB rotating weights (hi / interleaved)
  char* R1 = R0 + (size_t)22016 * 4096 * 2;        // 67.1MB wqk_lo; later xo,h2
  char* R2 = R1 + (size_t)8192 * 4096 * 2;         // 33.6MB h_hi,h_lo
  char* R3 = R2 + (size_t)2 * 2048 * 4096 * 2;     // 67.1MB qk hi/lo; later x1silu
  char* R4 = R3 + (size_t)2 * 2048 * 8192 * 2;     // 33.6MB ao, vT
  char* RT = R4 + (size_t)2 * 2048 * 4096 * 2;     // 1MB rope table
  (void)ws_size; (void)in_sizes; (void)n_in; (void)out_size;

  u16* wA     = (u16*)R0;
  u16* wB     = (u16*)R1;
  u16* h_hi   = (u16*)R2;
  u16* h_lo   = (u16*)(R2 + (size_t)2048 * 4096 * 2);
  u16* qk_hi  = (u16*)R3;
  u16* qk_lo  = (u16*)(R3 + (size_t)2048 * 8192 * 2);
  u16* ao     = (u16*)R4;
  u16* vT     = (u16*)(R4 + (size_t)2048 * 4096 * 2);
  float* xo   = (float*)R1;                         // wB dead after QK GEMM
  u16* h2     = (u16*)(R1 + (size_t)2048 * 4096 * 4);
  u16* x1silu = (u16*)R3;                           // qk dead after attn
  float* tab  = (float*)RT;

  dim3 tb(32, 8);

  rope_table_kernel<<<512, 256, 0, stream>>>(tab);
  rmsnorm_kernel<true><<<2048, 256, 0, stream>>>(x, g_attn, h_hi, h_lo);
  // fused Q|K projection: 8-phase 256^2 gemm8, K'=12288 (TRIK split 3-product)
  tconv_split_kernel<<<dim3(64, 64), tb, 0, stream>>>(wq, wA, wB, 4096, 4096);
  tconv_split_kernel<<<dim3(64, 64), tb, 0, stream>>>(wk, wA + (size_t)4096 * 4096, wB + (size_t)4096 * 4096, 4096, 4096);
  gemm8_kernel<2, true><<<dim3(32, 8), 512, 0, stream>>>(
      h_hi, h_lo, wA, wB, qk_hi, qk_lo, 2048, 8192, 12288, 4096, 4096);
  rope_inplace_kernel<<<32768, 256, 0, stream>>>(qk_hi, qk_lo, tab);
  // V projection with fused transpose: writes vT [d][s] directly
  tconv_kernel<<<dim3(64, 64), tb, 0, stream>>>(wv, wA, 4096, 4096);
  gemm8n_kernel<2><<<dim3(16, 16), 512, 0, stream>>>(h_hi, wA, vT, 2048, 4096, 4096, 4096, 4096);
  // attention (QBLK=128 via 4 waves x 2 q-groups)
  attn_kernel<<<dim3(16, 32), 256, 0, stream>>>(qk_hi, qk_lo, qk_hi + 4096, qk_lo + 4096, vT, ao);
  // xo = ao @ wo (f32)
  tconv_kernel<<<dim3(64, 64), tb, 0, stream>>>(wo, wA, 4096, 4096);
  gemm8n_kernel<0><<<dim3(16, 16), 512, 0, stream>>>(ao, wA, xo, 2048, 4096, 4096, 4096, 4096);
  rmsnorm_kernel<false><<<2048, 256, 0, stream>>>(xo, g_ffn, h2, nullptr);
  // FFN up with fused silu on the 256^2 8-phase structure
  tconv_ilv_kernel<<<dim3(172, 64), tb, 0, stream>>>(w1, wA, 4096, 11008, 0);
  tconv_ilv_kernel<<<dim3(172, 64), tb, 0, stream>>>(w3, wA, 4096, 11008, 128);
  gemm8_kernel<3, false><<<dim3(86, 8), 512, 0, stream>>>(
      h2, nullptr, wA, nullptr, x1silu, nullptr, 2048, 11008, 4096, 4096, 4096);
  // out = x1silu @ w2 : K=11008
  tconv_kernel<<<dim3(64, 172), tb, 0, stream>>>(w2, wA, 11008, 4096);
  gemm8n_kernel<0><<<dim3(16, 16), 512, 0, stream>>>(x1silu, wA, (float*)d_out, 2048, 4096, 11008, 11008, 11008);
}

// Round 16
// 1626.884 us; speedup vs baseline: 1.0296x; 1.0296x over previous
//
#include <hip/hip_runtime.h>
#include <math.h>

// ---------- types / helpers ----------
typedef unsigned short u16;
typedef short short8 __attribute__((ext_vector_type(8)));
typedef _Float16 half8 __attribute__((ext_vector_type(8)));
typedef float f32x4 __attribute__((ext_vector_type(4)));

#define DEV static __device__ __forceinline__

DEV float bf2f(u16 h) { union { unsigned int u; float f; } v; v.u = ((unsigned int)h) << 16; return v.f; }
DEV u16 f2bf(float f) {
  union { float f; unsigned int u; } v; v.f = f;
  unsigned int r = v.u + 0x7FFFu + ((v.u >> 16) & 1u);  // RNE
  return (u16)(r >> 16);
}
DEV u16 f2h(float f) { union { _Float16 h; u16 u; } v; v.h = (_Float16)f; return v.u; }
DEV float h2f(u16 b) { union { u16 u; _Float16 h; } v; v.u = b; return (float)v.h; }

DEV void gl_lds16(const void* g, void* l) {
  __builtin_amdgcn_global_load_lds(
      (const __attribute__((address_space(1))) unsigned int*)g,
      (__attribute__((address_space(3))) unsigned int*)l, 16, 0, 0);
}

template <int N> DEV void vm_wait() {
  if constexpr (N == 0) asm volatile("s_waitcnt vmcnt(0)" ::: "memory");
  else if constexpr (N == 6) asm volatile("s_waitcnt vmcnt(6)" ::: "memory");
  else if constexpr (N == 8) asm volatile("s_waitcnt vmcnt(8)" ::: "memory");
  else static_assert(N == 0 || N == 6 || N == 8, "add literal");
}

DEV void lgkm0_pin() {
  asm volatile("s_waitcnt lgkmcnt(0)" ::: "memory");
  __builtin_amdgcn_sched_barrier(0);
}

// XCD-aware block swizzle (bijective; all grids have nwg%8==0).
DEV void xcd_swizzle(int& bx, int& by) {
  int gx = gridDim.x, gy = gridDim.y;
  int lin = by * gx + bx;
  int xcd = lin & 7, i = lin >> 3;
  if ((gx & 7) == 0) {
    int cx = gx >> 3;
    bx = xcd * cx + i % cx;
    by = i / cx;
  } else {
    int cpx = (gx * gy) >> 3;
    int swz = xcd * cpx + i;
    bx = swz % gx;
    by = swz / gx;
  }
}

// ---------- RMSNorm: f32 [2048][4096] -> bf16 (optionally split hi/lo) ----------
template <bool SPLIT>
__global__ __launch_bounds__(256) void rmsnorm_kernel(
    const float* __restrict__ x, const float* __restrict__ g,
    u16* __restrict__ oh, u16* __restrict__ ol) {
  int row = blockIdx.x, t = threadIdx.x;
  const float* xr = x + (size_t)row * 4096;
  float4 vals[4];
  float s = 0.f;
#pragma unroll
  for (int i = 0; i < 4; i++) {
    vals[i] = ((const float4*)xr)[t + i * 256];
    s += vals[i].x * vals[i].x + vals[i].y * vals[i].y + vals[i].z * vals[i].z + vals[i].w * vals[i].w;
  }
#pragma unroll
  for (int m = 1; m < 64; m <<= 1) s += __shfl_xor(s, m);
  __shared__ float red[4];
  if ((t & 63) == 0) red[t >> 6] = s;
  __syncthreads();
  s = red[0] + red[1] + red[2] + red[3];
  float rinv = rsqrtf(s * (1.f / 4096.f) + 1.1920929e-07f);
#pragma unroll
  for (int i = 0; i < 4; i++) {
    float4 gv = ((const float4*)g)[t + i * 256];
    float4 v = vals[i];
    float f[4] = {v.x * rinv * gv.x, v.y * rinv * gv.y, v.z * rinv * gv.z, v.w * rinv * gv.w};
    ushort4 rh, rl;
    u16* hp = (u16*)&rh; u16* lp = (u16*)&rl;
#pragma unroll
    for (int j = 0; j < 4; j++) {
      u16 hi = f2bf(f[j]);
      hp[j] = hi;
      if (SPLIT) lp[j] = f2bf(f[j] - bf2f(hi));
    }
    ((ushort4*)(oh + (size_t)row * 4096))[t + i * 256] = rh;
    if (SPLIT) ((ushort4*)(ol + (size_t)row * 4096))[t + i * 256] = rl;
  }
}

// ---------- transpose-convert, 64x64 tiles: w f32 [K][N] -> wT bf16 [N][K] ----------
__global__ void tconv_kernel(const float* __restrict__ in, u16* __restrict__ out, int K, int N) {
  __shared__ float tile[64][65];
  int k0 = blockIdx.y * 64, n0 = blockIdx.x * 64;
  int tx = threadIdx.x, ty = threadIdx.y;
#pragma unroll
  for (int i = 0; i < 8; i++) {
    int r = ty + 8 * i;
    float2 v = *(const float2*)&in[(size_t)(k0 + r) * N + n0 + tx * 2];
    tile[r][tx * 2] = v.x;
    tile[r][tx * 2 + 1] = v.y;
  }
  __syncthreads();
#pragma unroll
  for (int i = 0; i < 8; i++) {
    int c = ty + 8 * i;
    ushort2 o;
    o.x = f2bf(tile[tx * 2][c]);
    o.y = f2bf(tile[tx * 2 + 1][c]);
    *(ushort2*)&out[(size_t)(n0 + c) * K + k0 + tx * 2] = o;
  }
}

// ---------- 64x64 transpose-convert, 128-col interleave (for [w1|w3] packing) ----------
__global__ void tconv_ilv_kernel(const float* __restrict__ in, u16* __restrict__ out,
                                 int K, int N, int off) {
  __shared__ float tile[64][65];
  int k0 = blockIdx.y * 64, n0 = blockIdx.x * 64;
  int tx = threadIdx.x, ty = threadIdx.y;
#pragma unroll
  for (int i = 0; i < 8; i++) {
    int r = ty + 8 * i;
    float2 v = *(const float2*)&in[(size_t)(k0 + r) * N + n0 + tx * 2];
    tile[r][tx * 2] = v.x;
    tile[r][tx * 2 + 1] = v.y;
  }
  __syncthreads();
#pragma unroll
  for (int i = 0; i < 8; i++) {
    int c = ty + 8 * i;
    int n = n0 + c;
    int orow = ((n >> 7) << 8) + (n & 127) + off;
    ushort2 o;
    o.x = f2bf(tile[tx * 2][c]);
    o.y = f2bf(tile[tx * 2 + 1][c]);
    *(ushort2*)&out[(size_t)orow * K + k0 + tx * 2] = o;
  }
}

// ---------- 64x64 transpose-convert split: w f32 [K][N] -> hi/lo bf16 [N][K] ----------
__global__ void tconv_split_kernel(const float* __restrict__ in, u16* __restrict__ oh,
                                   u16* __restrict__ ol, int K, int N) {
  __shared__ float tile[64][65];
  int k0 = blockIdx.y * 64, n0 = blockIdx.x * 64;
  int tx = threadIdx.x, ty = threadIdx.y;
#pragma unroll
  for (int i = 0; i < 8; i++) {
    int r = ty + 8 * i;
    float2 v = *(const float2*)&in[(size_t)(k0 + r) * N + n0 + tx * 2];
    tile[r][tx * 2] = v.x;
    tile[r][tx * 2 + 1] = v.y;
  }
  __syncthreads();
#pragma unroll
  for (int i = 0; i < 8; i++) {
    int c = ty + 8 * i;
    float f0 = tile[tx * 2][c], f1 = tile[tx * 2 + 1][c];
    u16 h0 = f2bf(f0), h1 = f2bf(f1);
    ushort2 vh, vl;
    vh.x = h0; vh.y = h1;
    vl.x = f2bf(f0 - bf2f(h0)); vl.y = f2bf(f1 - bf2f(h1));
    size_t idx = (size_t)(n0 + c) * K + k0 + tx * 2;
    *(ushort2*)&oh[idx] = vh;
    *(ushort2*)&ol[idx] = vl;
  }
}

// ---------- RoPE cos/sin table (double precision): tab[s][j] = {cos,sin} ----------
__global__ __launch_bounds__(256) void rope_table_kernel(float* __restrict__ tab) {
  int i = blockIdx.x * 256 + threadIdx.x;  // 2048*64
  int j = i & 63, s = i >> 6;
  double freq = pow(10000.0, -(double)j / 64.0);
  double ang = (double)s * freq;
  tab[i * 2] = (float)cos(ang);
  tab[i * 2 + 1] = (float)sin(ang);
}

// ---------- RoPE in place on fp16 [2048][8192]; one wave owns one 128-col slot ----------
// (wave-lockstep: all 128 reads precede all writes within the owning wave)
__global__ __launch_bounds__(256) void rope_inplace_kernel(
    u16* q, const float* __restrict__ tab) {
  int idx = blockIdx.x * 256 + threadIdx.x;  // (s, slot6, j)
  int j = idx & 63, hd = (idx >> 6) & 63, s = idx >> 12;
  size_t base = (size_t)s * 8192 + hd * 128;
  float xe = h2f(q[base + 2 * j]);
  float xo = h2f(q[base + 2 * j + 1]);
  float cs = tab[(s * 64 + j) * 2], sn = tab[(s * 64 + j) * 2 + 1];
  q[base + j] = f2h(xe * cs - xo * sn);
  q[base + 64 + j] = f2h(xe * sn + xo * cs);
}

// ---------- 8-phase 256x256 GEMM, 2-tiles-ahead staging (round-5 proven) ----------
// TRIK: K' = 3*Kseg, per-segment operand select: seg0 A*B, seg1 A2*B, seg2 A*B2.
// OUT: 0=f32, 1=bf16, 2=split hi/lo, 3=fused silu (interleaved [w1|w3]), 4=fp16.
template <int OUT, bool TRIK>
__global__ __launch_bounds__(512, 2) void gemm8_kernel(
    const u16* __restrict__ A, const u16* __restrict__ A2,
    const u16* __restrict__ B, const u16* __restrict__ B2,
    void* __restrict__ C, u16* __restrict__ C2,
    int M, int N, int K, int lda, int ldb) {
  __shared__ __attribute__((aligned(16))) u16 SMEM[65536];  // 128KB: A 64KB | B 64KB
  int t = threadIdx.x, l = t & 63, w = t >> 6;
  int bx = blockIdx.x, by = blockIdx.y;
  xcd_swizzle(bx, by);
  int m0 = by * 256, n0 = bx * 256;
  int wm = w >> 2, wn = w & 3, bh = wn >> 1;
  f32x4 acc[8][4] = {};
  int nk = K >> 6;

  auto AsP = [&](int d, int h) -> u16* { return SMEM + (d * 2 + h) * 8192; };
  auto BsP = [&](int d, int h) -> u16* { return SMEM + 32768 + (d * 2 + h) * 8192; };

  auto stageA = [&](int kt, int dd) {
    const u16* Ab = A; int kc = kt << 6;
    if (TRIK) { int seg = kt >> 6; Ab = (seg == 1) ? A2 : A; kc = (kt & 63) << 6; }
#pragma unroll
    for (int i = 0; i < 4; i++) {
      int id = i * 512 + t;
      int hh = id >> 10, idc = id & 1023;
      int r = idc >> 3, cb = idc & 7;
      int csw = ((cb * 16) ^ ((r & 7) << 4)) >> 1;
      gl_lds16(&Ab[(size_t)(m0 + hh * 128 + r) * lda + kc + csw], AsP(dd, hh) + idc * 8);
    }
  };
  auto stageB = [&](int kt, int dd) {
    const u16* Bb = B; int kc = kt << 6;
    if (TRIK) { int seg = kt >> 6; Bb = (seg == 2) ? B2 : B; kc = (kt & 63) << 6; }
#pragma unroll
    for (int i = 0; i < 4; i++) {
      int id = i * 512 + t;
      int hh = id >> 10, idc = id & 1023;
      int r = idc >> 3, cb = idc & 7;
      int csw = ((cb * 16) ^ ((r & 7) << 4)) >> 1;
      gl_lds16(&Bb[(size_t)(n0 + hh * 128 + r) * ldb + kc + csw], BsP(dd, hh) + idc * 8);
    }
  };

  int lq = l >> 4, lr = l & 15;
  short8 af[4][2], bf[4][2];
  auto rdA = [&](int d, int mh) {
    const char* Ax = (const char*)AsP(d, wm);
#pragma unroll
    for (int m = 0; m < 4; m++) {
      int r = mh * 64 + m * 16 + lr;
      int rb = r * 128, rx = (r & 7) << 4;
#pragma unroll
      for (int kh = 0; kh < 2; kh++)
        af[m][kh] = *(const short8*)(Ax + rb + ((kh * 64 + lq * 16) ^ rx));
    }
  };
  auto rdB2 = [&](int d, int nlo, int nhi) {
    const char* Bx = (const char*)BsP(d, bh);
#pragma unroll
    for (int n = 0; n < 4; n++) {
      if (n < nlo || n >= nhi) continue;
      int r = (wn & 1) * 64 + n * 16 + lr;
      int rb = r * 128, rx = (r & 7) << 4;
#pragma unroll
      for (int kh = 0; kh < 2; kh++)
        bf[n][kh] = *(const short8*)(Bx + rb + ((kh * 64 + lq * 16) ^ rx));
    }
  };
  auto mm8 = [&](int mo, int no) {
    __builtin_amdgcn_s_setprio(1);
#pragma unroll
    for (int m = 0; m < 4; m++)
#pragma unroll
      for (int n = 0; n < 2; n++)
#pragma unroll
        for (int kh = 0; kh < 2; kh++)
          acc[mo + m][no + n] =
              __builtin_amdgcn_mfma_f32_16x16x32_bf16(af[m][kh], bf[no + n][kh], acc[mo + m][no + n], 0, 0, 0);
    __builtin_amdgcn_s_setprio(0);
  };

  stageB(0, 0); stageA(0, 0);
  stageB(1, 1); stageA(1, 1);
  vm_wait<8>();
  __builtin_amdgcn_s_barrier();

  for (int kt = 0; kt < nk; ++kt) {
    int d = kt & 1;
    rdA(d, 0);
    rdB2(d, 0, 2);
    __builtin_amdgcn_s_barrier();
    lgkm0_pin();
    mm8(0, 0);
    __builtin_amdgcn_s_barrier();
    rdB2(d, 2, 4);
    __builtin_amdgcn_s_barrier();
    lgkm0_pin();
    mm8(0, 2);
    __builtin_amdgcn_s_barrier();
    rdA(d, 1);
    if (kt + 2 < nk) stageB(kt + 2, d);
    __builtin_amdgcn_s_barrier();
    lgkm0_pin();
    mm8(4, 2);
    __builtin_amdgcn_s_barrier();
    if (kt + 2 < nk) stageA(kt + 2, d);
    __builtin_amdgcn_s_barrier();
    mm8(4, 0);
    if (kt + 2 < nk) vm_wait<8>();
    else vm_wait<0>();
    __builtin_amdgcn_s_barrier();
  }

  if (OUT == 3) {
    __syncthreads();
    float* EPI = (float*)SMEM;  // 256 x 128 f32 = 128KB
    if (wn >= 2) {
#pragma unroll
      for (int m = 0; m < 8; m++)
#pragma unroll
        for (int i = 0; i < 4; i++) {
          int rl = wm * 128 + m * 16 + lq * 4 + i;
#pragma unroll
          for (int n = 0; n < 4; n++)
            EPI[rl * 128 + (wn - 2) * 64 + n * 16 + lr] = acc[m][n][i];
        }
    }
    __syncthreads();
    if (wn < 2) {
      u16* Ob = (u16*)C;
      int cb = n0 >> 1;
#pragma unroll
      for (int m = 0; m < 8; m++)
#pragma unroll
        for (int i = 0; i < 4; i++) {
          int rl = wm * 128 + m * 16 + lq * 4 + i;
          int row = m0 + rl;
#pragma unroll
          for (int n = 0; n < 4; n++) {
            float a = acc[m][n][i];
            float b = EPI[rl * 128 + wn * 64 + n * 16 + lr];
            float r = a * (b / (1.f + expf(-b)));
            Ob[(size_t)row * N + cb + wn * 64 + n * 16 + lr] = f2bf(r);
          }
        }
    }
    return;
  }

#pragma unroll
  for (int m = 0; m < 8; m++) {
#pragma unroll
    for (int i = 0; i < 4; i++) {
      int row = m0 + wm * 128 + m * 16 + lq * 4 + i;
      size_t rb = (size_t)row * N + n0 + wn * 64 + lr;
#pragma unroll
      for (int n = 0; n < 4; n++) {
        float f = acc[m][n][i];
        if (OUT == 0) ((float*)C)[rb + n * 16] = f;
        else if (OUT == 1) ((u16*)C)[rb + n * 16] = f2bf(f);
        else if (OUT == 4) ((u16*)C)[rb + n * 16] = f2h(f);
        else {
          u16 hi = f2bf(f);
          ((u16*)C)[rb + n * 16] = hi;
          C2[rb + n * 16] = f2bf(f - bf2f(hi));
        }
      }
    }
  }
}

// ---------- 2-phase 128x256 GEMM (round-5 proven; N=4096 shapes) ----------
// OUT: 0=f32, 1=bf16, 2=bf16 transposed [N][M].
template <int OUT>
__global__ __launch_bounds__(512, 2) void gemm8n_kernel(
    const u16* __restrict__ A, const u16* __restrict__ B, void* __restrict__ C,
    int M, int N, int K, int lda, int ldb) {
  __shared__ __attribute__((aligned(16))) u16 As[2][128 * 64];
  __shared__ __attribute__((aligned(16))) u16 Bs3[3][256 * 64];
  int t = threadIdx.x, l = t & 63, w = t >> 6;
  int bx = blockIdx.x, by = blockIdx.y;
  xcd_swizzle(bx, by);
  int m0 = by * 128, n0 = bx * 256;
  int wm = w >> 2, wn = w & 3;
  f32x4 acc[4][4] = {};
  int nk = K >> 6;

  auto stageA = [&](int kt, int dd) {
    int kc = kt << 6;
#pragma unroll
    for (int i = 0; i < 2; i++) {
      int id = i * 512 + t;
      int r = id >> 3, cb = id & 7;
      int csw = ((cb * 16) ^ ((r & 7) << 4)) >> 1;
      gl_lds16(&A[(size_t)(m0 + r) * lda + kc + csw], &As[dd][id * 8]);
    }
  };
  auto stageB = [&](int kt, int bb) {
    int kc = kt << 6;
#pragma unroll
    for (int i = 0; i < 4; i++) {
      int id = i * 512 + t;
      int r = id >> 3, cb = id & 7;
      int csw = ((cb * 16) ^ ((r & 7) << 4)) >> 1;
      gl_lds16(&B[(size_t)(n0 + r) * ldb + kc + csw], &Bs3[bb][id * 8]);
    }
  };

  int lq = l >> 4, lr = l & 15;
  short8 af0[4], af1[4], bf0[4], bf1[4];
  auto rdA4 = [&](short8 (&dst)[4], int d, int kh) {
    const char* Ax = (const char*)As[d];
#pragma unroll
    for (int m = 0; m < 4; m++) {
      int r = wm * 64 + m * 16 + lr;
      dst[m] = *(const short8*)(Ax + r * 128 + ((kh * 64 + lq * 16) ^ ((r & 7) << 4)));
    }
  };
  auto rdB4 = [&](short8 (&dst)[4], int bb, int kh) {
    const char* Bx = (const char*)Bs3[bb];
#pragma unroll
    for (int n = 0; n < 4; n++) {
      int r = wn * 64 + n * 16 + lr;
      dst[n] = *(const short8*)(Bx + r * 128 + ((kh * 64 + lq * 16) ^ ((r & 7) << 4)));
    }
  };
  auto mm16 = [&](short8 (&a)[4], short8 (&b)[4]) {
    __builtin_amdgcn_s_setprio(1);
#pragma unroll
    for (int m = 0; m < 4; m++)
#pragma unroll
      for (int n = 0; n < 4; n++)
        acc[m][n] = __builtin_amdgcn_mfma_f32_16x16x32_bf16(a[m], b[n], acc[m][n], 0, 0, 0);
    __builtin_amdgcn_s_setprio(0);
  };

  stageB(0, 0); stageA(0, 0);
  stageB(1, 1); stageA(1, 1);
  vm_wait<6>();
  __builtin_amdgcn_s_barrier();

  for (int kt = 0; kt < nk; ++kt) {
    int d = kt & 1;
    int bb = kt % 3, bb2 = (kt + 2) % 3;
    if (kt + 2 < nk) stageB(kt + 2, bb2);
    rdA4(af0, d, 0); rdB4(bf0, bb, 0);
    __builtin_amdgcn_s_barrier();
    lgkm0_pin();
    mm16(af0, bf0);
    __builtin_amdgcn_s_barrier();
    rdA4(af1, d, 1); rdB4(bf1, bb, 1);
    lgkm0_pin();
    __builtin_amdgcn_s_barrier();
    if (kt + 2 < nk) { stageA(kt + 2, d); vm_wait<6>(); }
    else vm_wait<0>();
    mm16(af1, bf1);
    __builtin_amdgcn_s_barrier();
  }
  if (OUT == 2) {
    u16* Cb = (u16*)C;
#pragma unroll
    for (int m = 0; m < 4; m++) {
      int sbase = m0 + wm * 64 + m * 16 + lq * 4;
#pragma unroll
      for (int n = 0; n < 4; n++) {
        int dg = n0 + wn * 64 + n * 16 + lr;
        ushort4 pk;
        pk.x = f2bf(acc[m][n][0]); pk.y = f2bf(acc[m][n][1]);
        pk.z = f2bf(acc[m][n][2]); pk.w = f2bf(acc[m][n][3]);
        *(ushort4*)&Cb[(size_t)dg * M + sbase] = pk;
      }
    }
    return;
  }
#pragma unroll
  for (int m = 0; m < 4; m++) {
#pragma unroll
    for (int i = 0; i < 4; i++) {
      int row = m0 + wm * 64 + m * 16 + lq * 4 + i;
      size_t rb = (size_t)row * N + n0 + wn * 64 + lr;
#pragma unroll
      for (int n = 0; n < 4; n++) {
        float f = acc[m][n][i];
        if (OUT == 0) ((float*)C)[rb + n * 16] = f;
        else ((u16*)C)[rb + n * 16] = f2bf(f);
      }
    }
  }
}

// ---------- flash attention (no scale, no mask), fp16 q/k ----------
// QBLK=128 via 4 waves x 2 q-groups (r15 structure). q,k fp16 (3-term-accurate
// values rounded to fp16): single-product QK^T (1 MFMA/frag vs 3), K staged
// fp16-only (32KB/tile). P/V/PV stay bf16 (baseline error path unchanged).
__global__ __launch_bounds__(256, 2) void attn_kernel(
    const u16* __restrict__ qf16, const u16* __restrict__ kf16,
    const u16* __restrict__ vt, u16* __restrict__ out) {
  const int QS = 8192;
  __shared__ __attribute__((aligned(16))) u16 KH[64 * 128];   // fp16 [kv][d], XOR-swizzled
  __shared__ __attribute__((aligned(16))) u16 Vl[128 * 64];   // bf16 [d][kv], XOR-swizzled
  __shared__ __attribute__((aligned(16))) u16 Pl[8][16 * 72]; // per (wave,group) [q][kv]
  int t = threadIdx.x, l = t & 63, w = t >> 6;
  int hd = blockIdx.y, q0 = blockIdx.x * 128;
  int lr = l & 15, lq = l >> 4;
  int qrow0 = q0 + (w * 2) * 16 + lr;
  int qrow1 = q0 + (w * 2 + 1) * 16 + lr;
  half8 qf[2][4];
#pragma unroll
  for (int g = 0; g < 2; g++) {
    size_t qoff = (size_t)(g ? qrow1 : qrow0) * QS + hd * 128 + lq * 8;
#pragma unroll
    for (int kc = 0; kc < 4; kc++)
      qf[g][kc] = *(const half8*)&qf16[qoff + kc * 32];
  }
  f32x4 accO[2][8] = {};
  float mrun[2] = {-__builtin_inff(), -__builtin_inff()};
  float lrun[2] = {0.f, 0.f};
  for (int kv0 = 0; kv0 < 2048; kv0 += 64) {
    // stage K fp16 [64][128] + V^T bf16 [128][64]; swizzled source, linear dest
#pragma unroll
    for (int i = 0; i < 4; i++) {
      int ci = i * 256 + t;
      int row = ci >> 4;
      int cb = (ci & 15) ^ (row & 7);
      gl_lds16(&kf16[(size_t)(kv0 + row) * QS + hd * 128 + cb * 8], &KH[ci * 8]);
    }
#pragma unroll
    for (int i = 0; i < 4; i++) {
      int ci = i * 256 + t;
      int row = ci >> 3;
      int cb = (ci & 7) ^ (row & 7);
      gl_lds16(&vt[((size_t)hd * 128 + row) * 2048 + kv0 + cb * 8], &Vl[ci * 8]);
    }
    __syncthreads();
#pragma unroll
    for (int g = 0; g < 2; g++) {
      // S^T = K @ Q^T (fp16 single product)
      f32x4 accS[4];
#pragma unroll
      for (int mm = 0; mm < 4; mm++) {
        accS[mm] = (f32x4){0.f, 0.f, 0.f, 0.f};
#pragma unroll
        for (int kc = 0; kc < 4; kc++) {
          int rowk = mm * 16 + lr;
          int phys = (rowk * 256 + kc * 64 + lq * 16) ^ ((rowk & 7) << 4);
          half8 a_h = *(const half8*)((const char*)KH + phys);
          accS[mm] = __builtin_amdgcn_mfma_f32_16x16x32_f16(a_h, qf[g][kc], accS[mm], 0, 0, 0);
        }
      }
      // online softmax; lane owns q-row lr, kv spread over {l^16,l^32}
      float tmax = -__builtin_inff();
#pragma unroll
      for (int mm = 0; mm < 4; mm++)
        tmax = fmaxf(tmax, fmaxf(fmaxf(accS[mm][0], accS[mm][1]), fmaxf(accS[mm][2], accS[mm][3])));
      tmax = fmaxf(tmax, __shfl_xor(tmax, 16));
      tmax = fmaxf(tmax, __shfl_xor(tmax, 32));
      float mnew = fmaxf(mrun[g], tmax);
      float scale = expf(mrun[g] - mnew);
      float psum = 0.f;
      u16* Pw = &Pl[w * 2 + g][0];
#pragma unroll
      for (int mm = 0; mm < 4; mm++) {
        float p0 = expf(accS[mm][0] - mnew), p1 = expf(accS[mm][1] - mnew);
        float p2 = expf(accS[mm][2] - mnew), p3 = expf(accS[mm][3] - mnew);
        psum += (p0 + p1) + (p2 + p3);
        ushort4 pk;
        pk.x = f2bf(p0); pk.y = f2bf(p1); pk.z = f2bf(p2); pk.w = f2bf(p3);
        *(ushort4*)&Pw[lr * 72 + mm * 16 + lq * 4] = pk;
      }
      psum += __shfl_xor(psum, 16);
      psum += __shfl_xor(psum, 32);
      lrun[g] = lrun[g] * scale + psum;
      mrun[g] = mnew;
#pragma unroll
      for (int mm = 0; mm < 8; mm++) accO[g][mm] = accO[g][mm] * scale;
      // O^T += V^T @ P^T (bf16)
#pragma unroll
      for (int kc2 = 0; kc2 < 2; kc2++) {
        short8 bp = *(const short8*)((const char*)Pw + lr * 144 + kc2 * 64 + lq * 16);
#pragma unroll
        for (int mm = 0; mm < 8; mm++) {
          int rowd = mm * 16 + lr;
          int phys = (rowd * 128 + kc2 * 64 + lq * 16) ^ ((rowd & 7) << 4);
          short8 av = *(const short8*)((const char*)Vl + phys);
          accO[g][mm] = __builtin_amdgcn_mfma_f32_16x16x32_bf16(av, bp, accO[g][mm], 0, 0, 0);
        }
      }
    }
    __syncthreads();
  }
#pragma unroll
  for (int g = 0; g < 2; g++) {
    float rinv = 1.f / lrun[g];
    int qrow = g ? qrow1 : qrow0;
#pragma unroll
    for (int mm = 0; mm < 8; mm++) {
      ushort4 pk;
      pk.x = f2bf(accO[g][mm][0] * rinv); pk.y = f2bf(accO[g][mm][1] * rinv);
      pk.z = f2bf(accO[g][mm][2] * rinv); pk.w = f2bf(accO[g][mm][3] * rinv);
      *(ushort4*)&out[(size_t)qrow * 4096 + hd * 128 + mm * 16 + lq * 4] = pk;
    }
  }
}

// ---------- launch ----------
extern "C" void kernel_launch(void* const* d_in, const int* in_sizes, int n_in,
                              void* d_out, int out_size, void* d_ws, size_t ws_size,
                              hipStream_t stream) {
  const float* x      = (const float*)d_in[0];
  const float* wq     = (const float*)d_in[1];
  const float* wk     = (const float*)d_in[2];
  const float* wv     = (const float*)d_in[3];
  const float* wo     = (const float*)d_in[4];
  const float* w1     = (const float*)d_in[5];
  const float* w2     = (const float*)d_in[6];
  const float* w3     = (const float*)d_in[7];
  const float* g_attn = (const float*)d_in[8];
  const float* g_ffn  = (const float*)d_in[9];

  char* ws = (char*)d_ws;
  // region layout (total ~350 MB)
  char* R0 = ws;                                   // 180.4MB rotating weights (hi / interleaved)
  char* R1 = R0 + (size_t)22016 * 4096 * 2;        // 67.1MB wqk_lo; later xo,h2
  char* R2 = R1 + (size_t)8192 * 4096 * 2;         // 33.6MB h_hi,h_lo
  char* R3 = R2 + (size_t)2 * 2048 * 4096 * 2;     // 33.6MB qk fp16; later x1silu (spans R4)
  char* R4 = R3 + (size_t)2048 * 8192 * 2;         // 33.6MB ao, vT
  char* RT = R4 + (size_t)2 * 2048 * 4096 * 2;     // 1MB rope table
  (void)ws_size; (void)in_sizes; (void)n_in; (void)out_size;

  u16* wA     = (u16*)R0;
  u16* wB     = (u16*)R1;
  u16* h_hi   = (u16*)R2;
  u16* h_lo   = (u16*)(R2 + (size_t)2048 * 4096 * 2);
  u16* qk     = (u16*)R3;                           // fp16 [2048][8192]: q | k
  u16* ao     = (u16*)R4;
  u16* vT     = (u16*)(R4 + (size_t)2048 * 4096 * 2);
  float* xo   = (float*)R1;                         // wB dead after QK GEMM
  u16* h2     = (u16*)(R1 + (size_t)2048 * 4096 * 4);
  u16* x1silu = (u16*)R3;                           // qk dead after attn (spans into R4... no: 2048*11008*2=45MB > R3 33.6MB; spans into R4's ao region — ao still live!)
  float* tab  = (float*)RT;
  // x1silu needs 45MB: place it at R3 (33.6MB) + first 11.5MB of R4. ao occupies
  // R4[0..16.8MB). CONFLICT -> place x1silu at R2 instead (h_hi/h_lo dead after
  // attention? h_hi needed for V proj (done before attn), h_lo dead after QK).
  // Safer: x1silu = R3 (33.6MB) .. spans into R4 only if >33.6MB. 2048*11008*2 =
  // 45.1MB. Use R2 (33.6) + R3 head? h2 lives in R1. After attn: h_hi,h_lo dead,
  // qk dead -> contiguous R2+R3 = 67.2MB free. x1silu = R2.
  x1silu = (u16*)R2;

  dim3 tb(32, 8);

  rope_table_kernel<<<512, 256, 0, stream>>>(tab);
  rmsnorm_kernel<true><<<2048, 256, 0, stream>>>(x, g_attn, h_hi, h_lo);
  // fused Q|K projection: 8-phase 256^2 gemm8, K'=12288 (TRIK split 3-product), fp16 out
  tconv_split_kernel<<<dim3(64, 64), tb, 0, stream>>>(wq, wA, wB, 4096, 4096);
  tconv_split_kernel<<<dim3(64, 64), tb, 0, stream>>>(wk, wA + (size_t)4096 * 4096, wB + (size_t)4096 * 4096, 4096, 4096);
  gemm8_kernel<4, true><<<dim3(32, 8), 512, 0, stream>>>(
      h_hi, h_lo, wA, wB, qk, nullptr, 2048, 8192, 12288, 4096, 4096);
  rope_inplace_kernel<<<32768, 256, 0, stream>>>(qk, tab);
  // V projection with fused transpose: writes vT [d][s] directly
  tconv_kernel<<<dim3(64, 64), tb, 0, stream>>>(wv, wA, 4096, 4096);
  gemm8n_kernel<2><<<dim3(16, 16), 512, 0, stream>>>(h_hi, wA, vT, 2048, 4096, 4096, 4096, 4096);
  // attention (QBLK=128 via 4 waves x 2 q-groups; fp16 q/k)
  attn_kernel<<<dim3(16, 32), 256, 0, stream>>>(qk, qk + 4096, vT, ao);
  // xo = ao @ wo (f32)
  tconv_kernel<<<dim3(64, 64), tb, 0, stream>>>(wo, wA, 4096, 4096);
  gemm8n_kernel<0><<<dim3(16, 16), 512, 0, stream>>>(ao, wA, xo, 2048, 4096, 4096, 4096, 4096);
  rmsnorm_kernel<false><<<2048, 256, 0, stream>>>(xo, g_ffn, h2, nullptr);
  // FFN up with fused silu on the 256^2 8-phase structure
  tconv_ilv_kernel<<<dim3(172, 64), tb, 0, stream>>>(w1, wA, 4096, 11008, 0);
  tconv_ilv_kernel<<<dim3(172, 64), tb, 0, stream>>>(w3, wA, 4096, 11008, 128);
  gemm8_kernel<3, false><<<dim3(86, 8), 512, 0, stream>>>(
      h2, nullptr, wA, nullptr, x1silu, nullptr, 2048, 11008, 4096, 4096, 4096);
  // out = x1silu @ w2 : K=11008
  tconv_kernel<<<dim3(64, 172), tb, 0, stream>>>(w2, wA, 11008, 4096);
  gemm8n_kernel<0><<<dim3(16, 16), 512, 0, stream>>>(x1silu, wA, (float*)d_out, 2048, 4096, 11008, 11008, 11008);
}

// Round 17
// 1468.396 us; speedup vs baseline: 1.1407x; 1.1079x over previous
//
#include <hip/hip_runtime.h>
#include <math.h>

// ---------- types / helpers ----------
typedef unsigned short u16;
typedef short short8 __attribute__((ext_vector_type(8)));
typedef _Float16 half8 __attribute__((ext_vector_type(8)));
typedef float f32x4 __attribute__((ext_vector_type(4)));

#define DEV static __device__ __forceinline__

DEV float bf2f(u16 h) { union { unsigned int u; float f; } v; v.u = ((unsigned int)h) << 16; return v.f; }
DEV u16 f2bf(float f) {
  union { float f; unsigned int u; } v; v.f = f;
  unsigned int r = v.u + 0x7FFFu + ((v.u >> 16) & 1u);  // RNE
  return (u16)(r >> 16);
}
DEV u16 f2h(float f) { union { _Float16 h; u16 u; } v; v.h = (_Float16)f; return v.u; }
DEV float h2f(u16 b) { union { u16 u; _Float16 h; } v; v.u = b; return (float)v.h; }

DEV void gl_lds16(const void* g, void* l) {
  __builtin_amdgcn_global_load_lds(
      (const __attribute__((address_space(1))) unsigned int*)g,
      (__attribute__((address_space(3))) unsigned int*)l, 16, 0, 0);
}

template <int N> DEV void vm_wait() {
  if constexpr (N == 0) asm volatile("s_waitcnt vmcnt(0)" ::: "memory");
  else if constexpr (N == 6) asm volatile("s_waitcnt vmcnt(6)" ::: "memory");
  else if constexpr (N == 8) asm volatile("s_waitcnt vmcnt(8)" ::: "memory");
  else static_assert(N == 0 || N == 6 || N == 8, "add literal");
}

DEV void lgkm0_pin() {
  asm volatile("s_waitcnt lgkmcnt(0)" ::: "memory");
  __builtin_amdgcn_sched_barrier(0);
}

// generic MFMA over bf16 (DT=0) or fp16 (DT=1) fragments held in short8
template <int DT>
DEV f32x4 mm_frag(short8 a, short8 b, f32x4 c) {
  if constexpr (DT == 0)
    return __builtin_amdgcn_mfma_f32_16x16x32_bf16(a, b, c, 0, 0, 0);
  else
    return __builtin_amdgcn_mfma_f32_16x16x32_f16(*(half8*)&a, *(half8*)&b, c, 0, 0, 0);
}

// XCD-aware block swizzle (bijective; all grids have nwg%8==0).
DEV void xcd_swizzle(int& bx, int& by) {
  int gx = gridDim.x, gy = gridDim.y;
  int lin = by * gx + bx;
  int xcd = lin & 7, i = lin >> 3;
  if ((gx & 7) == 0) {
    int cx = gx >> 3;
    bx = xcd * cx + i % cx;
    by = i / cx;
  } else {
    int cpx = (gx * gy) >> 3;
    int swz = xcd * cpx + i;
    bx = swz % gx;
    by = swz / gx;
  }
}

// ---------- RMSNorm: f32 [2048][4096] -> SPLIT? fp16 hi/lo : bf16 ----------
template <bool SPLIT>
__global__ __launch_bounds__(256) void rmsnorm_kernel(
    const float* __restrict__ x, const float* __restrict__ g,
    u16* __restrict__ oh, u16* __restrict__ ol) {
  int row = blockIdx.x, t = threadIdx.x;
  const float* xr = x + (size_t)row * 4096;
  float4 vals[4];
  float s = 0.f;
#pragma unroll
  for (int i = 0; i < 4; i++) {
    vals[i] = ((const float4*)xr)[t + i * 256];
    s += vals[i].x * vals[i].x + vals[i].y * vals[i].y + vals[i].z * vals[i].z + vals[i].w * vals[i].w;
  }
#pragma unroll
  for (int m = 1; m < 64; m <<= 1) s += __shfl_xor(s, m);
  __shared__ float red[4];
  if ((t & 63) == 0) red[t >> 6] = s;
  __syncthreads();
  s = red[0] + red[1] + red[2] + red[3];
  float rinv = rsqrtf(s * (1.f / 4096.f) + 1.1920929e-07f);
#pragma unroll
  for (int i = 0; i < 4; i++) {
    float4 gv = ((const float4*)g)[t + i * 256];
    float4 v = vals[i];
    float f[4] = {v.x * rinv * gv.x, v.y * rinv * gv.y, v.z * rinv * gv.z, v.w * rinv * gv.w};
    ushort4 rh, rl;
    u16* hp = (u16*)&rh; u16* lp = (u16*)&rl;
#pragma unroll
    for (int j = 0; j < 4; j++) {
      if (SPLIT) {
        u16 hi = f2h(f[j]);
        hp[j] = hi;
        lp[j] = f2h(f[j] - h2f(hi));
      } else {
        hp[j] = f2bf(f[j]);
      }
    }
    ((ushort4*)(oh + (size_t)row * 4096))[t + i * 256] = rh;
    if (SPLIT) ((ushort4*)(ol + (size_t)row * 4096))[t + i * 256] = rl;
  }
}

// ---------- transpose-convert, 64x64 tiles: w f32 [K][N] -> wT (bf16|fp16) [N][K] ----------
template <bool F16>
__global__ void tconv_kernel(const float* __restrict__ in, u16* __restrict__ out, int K, int N) {
  __shared__ float tile[64][65];
  int k0 = blockIdx.y * 64, n0 = blockIdx.x * 64;
  int tx = threadIdx.x, ty = threadIdx.y;
#pragma unroll
  for (int i = 0; i < 8; i++) {
    int r = ty + 8 * i;
    float2 v = *(const float2*)&in[(size_t)(k0 + r) * N + n0 + tx * 2];
    tile[r][tx * 2] = v.x;
    tile[r][tx * 2 + 1] = v.y;
  }
  __syncthreads();
#pragma unroll
  for (int i = 0; i < 8; i++) {
    int c = ty + 8 * i;
    ushort2 o;
    o.x = F16 ? f2h(tile[tx * 2][c]) : f2bf(tile[tx * 2][c]);
    o.y = F16 ? f2h(tile[tx * 2 + 1][c]) : f2bf(tile[tx * 2 + 1][c]);
    *(ushort2*)&out[(size_t)(n0 + c) * K + k0 + tx * 2] = o;
  }
}

// ---------- 64x64 transpose-convert, 128-col interleave (for [w1|w3] packing) ----------
__global__ void tconv_ilv_kernel(const float* __restrict__ in, u16* __restrict__ out,
                                 int K, int N, int off) {
  __shared__ float tile[64][65];
  int k0 = blockIdx.y * 64, n0 = blockIdx.x * 64;
  int tx = threadIdx.x, ty = threadIdx.y;
#pragma unroll
  for (int i = 0; i < 8; i++) {
    int r = ty + 8 * i;
    float2 v = *(const float2*)&in[(size_t)(k0 + r) * N + n0 + tx * 2];
    tile[r][tx * 2] = v.x;
    tile[r][tx * 2 + 1] = v.y;
  }
  __syncthreads();
#pragma unroll
  for (int i = 0; i < 8; i++) {
    int c = ty + 8 * i;
    int n = n0 + c;
    int orow = ((n >> 7) << 8) + (n & 127) + off;
    ushort2 o;
    o.x = f2bf(tile[tx * 2][c]);
    o.y = f2bf(tile[tx * 2 + 1][c]);
    *(ushort2*)&out[(size_t)orow * K + k0 + tx * 2] = o;
  }
}

// ---------- RoPE cos/sin table (double precision): tab[s][j] = {cos,sin} ----------
__global__ __launch_bounds__(256) void rope_table_kernel(float* __restrict__ tab) {
  int i = blockIdx.x * 256 + threadIdx.x;  // 2048*64
  int j = i & 63, s = i >> 6;
  double freq = pow(10000.0, -(double)j / 64.0);
  double ang = (double)s * freq;
  tab[i * 2] = (float)cos(ang);
  tab[i * 2 + 1] = (float)sin(ang);
}

// ---------- RoPE in place on fp16 [2048][8192]; one wave owns one 128-col slot ----------
__global__ __launch_bounds__(256) void rope_inplace_kernel(
    u16* q, const float* __restrict__ tab) {
  int idx = blockIdx.x * 256 + threadIdx.x;  // (s, slot6, j)
  int j = idx & 63, hd = (idx >> 6) & 63, s = idx >> 12;
  size_t base = (size_t)s * 8192 + hd * 128;
  float xe = h2f(q[base + 2 * j]);
  float xo = h2f(q[base + 2 * j + 1]);
  float cs = tab[(s * 64 + j) * 2], sn = tab[(s * 64 + j) * 2 + 1];
  q[base + j] = f2h(xe * cs - xo * sn);
  q[base + 64 + j] = f2h(xe * sn + xo * cs);
}

// ---------- 8-phase 256x256 GEMM, 2-tiles-ahead staging (round-5 proven) ----------
// TRIK (2-seg): K' = 2*Kseg; seg0 A*B, seg1 A2*B (fp16 split-activation product).
// DT: MFMA input dtype (0=bf16, 1=fp16).
// OUT: 0=f32, 1=bf16, 3=fused silu (interleaved [w1|w3]), 4=fp16.
template <int OUT, bool TRIK, int DT>
__global__ __launch_bounds__(512, 2) void gemm8_kernel(
    const u16* __restrict__ A, const u16* __restrict__ A2,
    const u16* __restrict__ B,
    void* __restrict__ C,
    int M, int N, int K, int lda, int ldb) {
  __shared__ __attribute__((aligned(16))) u16 SMEM[65536];  // 128KB: A 64KB | B 64KB
  int t = threadIdx.x, l = t & 63, w = t >> 6;
  int bx = blockIdx.x, by = blockIdx.y;
  xcd_swizzle(bx, by);
  int m0 = by * 256, n0 = bx * 256;
  int wm = w >> 2, wn = w & 3, bh = wn >> 1;
  f32x4 acc[8][4] = {};
  int nk = K >> 6;

  auto AsP = [&](int d, int h) -> u16* { return SMEM + (d * 2 + h) * 8192; };
  auto BsP = [&](int d, int h) -> u16* { return SMEM + 32768 + (d * 2 + h) * 8192; };

  auto stageA = [&](int kt, int dd) {
    const u16* Ab = A; int kc = kt << 6;
    if (TRIK) { int seg = kt >> 6; Ab = (seg == 1) ? A2 : A; kc = (kt & 63) << 6; }
#pragma unroll
    for (int i = 0; i < 4; i++) {
      int id = i * 512 + t;
      int hh = id >> 10, idc = id & 1023;
      int r = idc >> 3, cb = idc & 7;
      int csw = ((cb * 16) ^ ((r & 7) << 4)) >> 1;
      gl_lds16(&Ab[(size_t)(m0 + hh * 128 + r) * lda + kc + csw], AsP(dd, hh) + idc * 8);
    }
  };
  auto stageB = [&](int kt, int dd) {
    int kc = kt << 6;
    if (TRIK) kc = (kt & 63) << 6;  // B identical across segments
#pragma unroll
    for (int i = 0; i < 4; i++) {
      int id = i * 512 + t;
      int hh = id >> 10, idc = id & 1023;
      int r = idc >> 3, cb = idc & 7;
      int csw = ((cb * 16) ^ ((r & 7) << 4)) >> 1;
      gl_lds16(&B[(size_t)(n0 + hh * 128 + r) * ldb + kc + csw], BsP(dd, hh) + idc * 8);
    }
  };

  int lq = l >> 4, lr = l & 15;
  short8 af[4][2], bf[4][2];
  auto rdA = [&](int d, int mh) {
    const char* Ax = (const char*)AsP(d, wm);
#pragma unroll
    for (int m = 0; m < 4; m++) {
      int r = mh * 64 + m * 16 + lr;
      int rb = r * 128, rx = (r & 7) << 4;
#pragma unroll
      for (int kh = 0; kh < 2; kh++)
        af[m][kh] = *(const short8*)(Ax + rb + ((kh * 64 + lq * 16) ^ rx));
    }
  };
  auto rdB2 = [&](int d, int nlo, int nhi) {
    const char* Bx = (const char*)BsP(d, bh);
#pragma unroll
    for (int n = 0; n < 4; n++) {
      if (n < nlo || n >= nhi) continue;
      int r = (wn & 1) * 64 + n * 16 + lr;
      int rb = r * 128, rx = (r & 7) << 4;
#pragma unroll
      for (int kh = 0; kh < 2; kh++)
        bf[n][kh] = *(const short8*)(Bx + rb + ((kh * 64 + lq * 16) ^ rx));
    }
  };
  auto mm8 = [&](int mo, int no) {
    __builtin_amdgcn_s_setprio(1);
#pragma unroll
    for (int m = 0; m < 4; m++)
#pragma unroll
      for (int n = 0; n < 2; n++)
#pragma unroll
        for (int kh = 0; kh < 2; kh++)
          acc[mo + m][no + n] = mm_frag<DT>(af[m][kh], bf[no + n][kh], acc[mo + m][no + n]);
    __builtin_amdgcn_s_setprio(0);
  };

  stageB(0, 0); stageA(0, 0);
  stageB(1, 1); stageA(1, 1);
  vm_wait<8>();
  __builtin_amdgcn_s_barrier();

  for (int kt = 0; kt < nk; ++kt) {
    int d = kt & 1;
    rdA(d, 0);
    rdB2(d, 0, 2);
    __builtin_amdgcn_s_barrier();
    lgkm0_pin();
    mm8(0, 0);
    __builtin_amdgcn_s_barrier();
    rdB2(d, 2, 4);
    __builtin_amdgcn_s_barrier();
    lgkm0_pin();
    mm8(0, 2);
    __builtin_amdgcn_s_barrier();
    rdA(d, 1);
    if (kt + 2 < nk) stageB(kt + 2, d);
    __builtin_amdgcn_s_barrier();
    lgkm0_pin();
    mm8(4, 2);
    __builtin_amdgcn_s_barrier();
    if (kt + 2 < nk) stageA(kt + 2, d);
    __builtin_amdgcn_s_barrier();
    mm8(4, 0);
    if (kt + 2 < nk) vm_wait<8>();
    else vm_wait<0>();
    __builtin_amdgcn_s_barrier();
  }

  if (OUT == 3) {
    __syncthreads();
    float* EPI = (float*)SMEM;  // 256 x 128 f32 = 128KB
    if (wn >= 2) {
#pragma unroll
      for (int m = 0; m < 8; m++)
#pragma unroll
        for (int i = 0; i < 4; i++) {
          int rl = wm * 128 + m * 16 + lq * 4 + i;
#pragma unroll
          for (int n = 0; n < 4; n++)
            EPI[rl * 128 + (wn - 2) * 64 + n * 16 + lr] = acc[m][n][i];
        }
    }
    __syncthreads();
    if (wn < 2) {
      u16* Ob = (u16*)C;
      int cb = n0 >> 1;
#pragma unroll
      for (int m = 0; m < 8; m++)
#pragma unroll
        for (int i = 0; i < 4; i++) {
          int rl = wm * 128 + m * 16 + lq * 4 + i;
          int row = m0 + rl;
#pragma unroll
          for (int n = 0; n < 4; n++) {
            float a = acc[m][n][i];
            float b = EPI[rl * 128 + wn * 64 + n * 16 + lr];
            float r = a * (b / (1.f + expf(-b)));
            Ob[(size_t)row * N + cb + wn * 64 + n * 16 + lr] = f2bf(r);
          }
        }
    }
    return;
  }

#pragma unroll
  for (int m = 0; m < 8; m++) {
#pragma unroll
    for (int i = 0; i < 4; i++) {
      int row = m0 + wm * 128 + m * 16 + lq * 4 + i;
      size_t rb = (size_t)row * N + n0 + wn * 64 + lr;
#pragma unroll
      for (int n = 0; n < 4; n++) {
        float f = acc[m][n][i];
        if (OUT == 0) ((float*)C)[rb + n * 16] = f;
        else if (OUT == 1) ((u16*)C)[rb + n * 16] = f2bf(f);
        else ((u16*)C)[rb + n * 16] = f2h(f);
      }
    }
  }
}

// ---------- 2-phase 128x256 GEMM (round-5 proven; N=4096 shapes) ----------
// OUT: 0=f32, 1=bf16, 2=transposed [N][M] (bf16 if DT=0, fp16 if DT=1).
template <int OUT, int DT>
__global__ __launch_bounds__(512, 2) void gemm8n_kernel(
    const u16* __restrict__ A, const u16* __restrict__ B, void* __restrict__ C,
    int M, int N, int K, int lda, int ldb) {
  __shared__ __attribute__((aligned(16))) u16 As[2][128 * 64];
  __shared__ __attribute__((aligned(16))) u16 Bs3[3][256 * 64];
  int t = threadIdx.x, l = t & 63, w = t >> 6;
  int bx = blockIdx.x, by = blockIdx.y;
  xcd_swizzle(bx, by);
  int m0 = by * 128, n0 = bx * 256;
  int wm = w >> 2, wn = w & 3;
  f32x4 acc[4][4] = {};
  int nk = K >> 6;

  auto stageA = [&](int kt, int dd) {
    int kc = kt << 6;
#pragma unroll
    for (int i = 0; i < 2; i++) {
      int id = i * 512 + t;
      int r = id >> 3, cb = id & 7;
      int csw = ((cb * 16) ^ ((r & 7) << 4)) >> 1;
      gl_lds16(&A[(size_t)(m0 + r) * lda + kc + csw], &As[dd][id * 8]);
    }
  };
  auto stageB = [&](int kt, int bb) {
    int kc = kt << 6;
#pragma unroll
    for (int i = 0; i < 4; i++) {
      int id = i * 512 + t;
      int r = id >> 3, cb = id & 7;
      int csw = ((cb * 16) ^ ((r & 7) << 4)) >> 1;
      gl_lds16(&B[(size_t)(n0 + r) * ldb + kc + csw], &Bs3[bb][id * 8]);
    }
  };

  int lq = l >> 4, lr = l & 15;
  short8 af0[4], af1[4], bf0[4], bf1[4];
  auto rdA4 = [&](short8 (&dst)[4], int d, int kh) {
    const char* Ax = (const char*)As[d];
#pragma unroll
    for (int m = 0; m < 4; m++) {
      int r = wm * 64 + m * 16 + lr;
      dst[m] = *(const short8*)(Ax + r * 128 + ((kh * 64 + lq * 16) ^ ((r & 7) << 4)));
    }
  };
  auto rdB4 = [&](short8 (&dst)[4], int bb, int kh) {
    const char* Bx = (const char*)Bs3[bb];
#pragma unroll
    for (int n = 0; n < 4; n++) {
      int r = wn * 64 + n * 16 + lr;
      dst[n] = *(const short8*)(Bx + r * 128 + ((kh * 64 + lq * 16) ^ ((r & 7) << 4)));
    }
  };
  auto mm16 = [&](short8 (&a)[4], short8 (&b)[4]) {
    __builtin_amdgcn_s_setprio(1);
#pragma unroll
    for (int m = 0; m < 4; m++)
#pragma unroll
      for (int n = 0; n < 4; n++)
        acc[m][n] = mm_frag<DT>(a[m], b[n], acc[m][n]);
    __builtin_amdgcn_s_setprio(0);
  };

  stageB(0, 0); stageA(0, 0);
  stageB(1, 1); stageA(1, 1);
  vm_wait<6>();
  __builtin_amdgcn_s_barrier();

  for (int kt = 0; kt < nk; ++kt) {
    int d = kt & 1;
    int bb = kt % 3, bb2 = (kt + 2) % 3;
    if (kt + 2 < nk) stageB(kt + 2, bb2);
    rdA4(af0, d, 0); rdB4(bf0, bb, 0);
    __builtin_amdgcn_s_barrier();
    lgkm0_pin();
    mm16(af0, bf0);
    __builtin_amdgcn_s_barrier();
    rdA4(af1, d, 1); rdB4(bf1, bb, 1);
    lgkm0_pin();
    __builtin_amdgcn_s_barrier();
    if (kt + 2 < nk) { stageA(kt + 2, d); vm_wait<6>(); }
    else vm_wait<0>();
    mm16(af1, bf1);
    __builtin_amdgcn_s_barrier();
  }
  if (OUT == 2) {
    u16* Cb = (u16*)C;
#pragma unroll
    for (int m = 0; m < 4; m++) {
      int sbase = m0 + wm * 64 + m * 16 + lq * 4;
#pragma unroll
      for (int n = 0; n < 4; n++) {
        int dg = n0 + wn * 64 + n * 16 + lr;
        ushort4 pk;
        if (DT == 1) {
          pk.x = f2h(acc[m][n][0]); pk.y = f2h(acc[m][n][1]);
          pk.z = f2h(acc[m][n][2]); pk.w = f2h(acc[m][n][3]);
        } else {
          pk.x = f2bf(acc[m][n][0]); pk.y = f2bf(acc[m][n][1]);
          pk.z = f2bf(acc[m][n][2]); pk.w = f2bf(acc[m][n][3]);
        }
        *(ushort4*)&Cb[(size_t)dg * M + sbase] = pk;
      }
    }
    return;
  }
#pragma unroll
  for (int m = 0; m < 4; m++) {
#pragma unroll
    for (int i = 0; i < 4; i++) {
      int row = m0 + wm * 64 + m * 16 + lq * 4 + i;
      size_t rb = (size_t)row * N + n0 + wn * 64 + lr;
#pragma unroll
      for (int n = 0; n < 4; n++) {
        float f = acc[m][n][i];
        if (OUT == 0) ((float*)C)[rb + n * 16] = f;
        else ((u16*)C)[rb + n * 16] = f2bf(f);
      }
    }
  }
}

// ---------- flash attention (no scale, no mask), full fp16 q/k/v/p ----------
// QBLK=128 via 4 waves x 2 q-groups. Single-product fp16 QK^T; fp16 P and V
// (strictly tighter rounding than bf16). Output bf16.
__global__ __launch_bounds__(256, 2) void attn_kernel(
    const u16* __restrict__ qf16, const u16* __restrict__ kf16,
    const u16* __restrict__ vt, u16* __restrict__ out) {
  const int QS = 8192;
  __shared__ __attribute__((aligned(16))) u16 KH[64 * 128];   // fp16 [kv][d], XOR-swizzled
  __shared__ __attribute__((aligned(16))) u16 Vl[128 * 64];   // fp16 [d][kv], XOR-swizzled
  __shared__ __attribute__((aligned(16))) u16 Pl[8][16 * 72]; // fp16 per (wave,group) [q][kv]
  int t = threadIdx.x, l = t & 63, w = t >> 6;
  int hd = blockIdx.y, q0 = blockIdx.x * 128;
  int lr = l & 15, lq = l >> 4;
  int qrow0 = q0 + (w * 2) * 16 + lr;
  int qrow1 = q0 + (w * 2 + 1) * 16 + lr;
  half8 qf[2][4];
#pragma unroll
  for (int g = 0; g < 2; g++) {
    size_t qoff = (size_t)(g ? qrow1 : qrow0) * QS + hd * 128 + lq * 8;
#pragma unroll
    for (int kc = 0; kc < 4; kc++)
      qf[g][kc] = *(const half8*)&qf16[qoff + kc * 32];
  }
  f32x4 accO[2][8] = {};
  float mrun[2] = {-__builtin_inff(), -__builtin_inff()};
  float lrun[2] = {0.f, 0.f};
  for (int kv0 = 0; kv0 < 2048; kv0 += 64) {
#pragma unroll
    for (int i = 0; i < 4; i++) {
      int ci = i * 256 + t;
      int row = ci >> 4;
      int cb = (ci & 15) ^ (row & 7);
      gl_lds16(&kf16[(size_t)(kv0 + row) * QS + hd * 128 + cb * 8], &KH[ci * 8]);
    }
#pragma unroll
    for (int i = 0; i < 4; i++) {
      int ci = i * 256 + t;
      int row = ci >> 3;
      int cb = (ci & 7) ^ (row & 7);
      gl_lds16(&vt[((size_t)hd * 128 + row) * 2048 + kv0 + cb * 8], &Vl[ci * 8]);
    }
    __syncthreads();
#pragma unroll
    for (int g = 0; g < 2; g++) {
      f32x4 accS[4];
#pragma unroll
      for (int mm = 0; mm < 4; mm++) {
        accS[mm] = (f32x4){0.f, 0.f, 0.f, 0.f};
#pragma unroll
        for (int kc = 0; kc < 4; kc++) {
          int rowk = mm * 16 + lr;
          int phys = (rowk * 256 + kc * 64 + lq * 16) ^ ((rowk & 7) << 4);
          half8 a_h = *(const half8*)((const char*)KH + phys);
          accS[mm] = __builtin_amdgcn_mfma_f32_16x16x32_f16(a_h, qf[g][kc], accS[mm], 0, 0, 0);
        }
      }
      float tmax = -__builtin_inff();
#pragma unroll
      for (int mm = 0; mm < 4; mm++)
        tmax = fmaxf(tmax, fmaxf(fmaxf(accS[mm][0], accS[mm][1]), fmaxf(accS[mm][2], accS[mm][3])));
      tmax = fmaxf(tmax, __shfl_xor(tmax, 16));
      tmax = fmaxf(tmax, __shfl_xor(tmax, 32));
      float mnew = fmaxf(mrun[g], tmax);
      float scale = expf(mrun[g] - mnew);
      float psum = 0.f;
      u16* Pw = &Pl[w * 2 + g][0];
#pragma unroll
      for (int mm = 0; mm < 4; mm++) {
        float p0 = expf(accS[mm][0] - mnew), p1 = expf(accS[mm][1] - mnew);
        float p2 = expf(accS[mm][2] - mnew), p3 = expf(accS[mm][3] - mnew);
        psum += (p0 + p1) + (p2 + p3);
        ushort4 pk;
        pk.x = f2h(p0); pk.y = f2h(p1); pk.z = f2h(p2); pk.w = f2h(p3);
        *(ushort4*)&Pw[lr * 72 + mm * 16 + lq * 4] = pk;
      }
      psum += __shfl_xor(psum, 16);
      psum += __shfl_xor(psum, 32);
      lrun[g] = lrun[g] * scale + psum;
      mrun[g] = mnew;
#pragma unroll
      for (int mm = 0; mm < 8; mm++) accO[g][mm] = accO[g][mm] * scale;
#pragma unroll
      for (int kc2 = 0; kc2 < 2; kc2++) {
        half8 bp = *(const half8*)((const char*)Pw + lr * 144 + kc2 * 64 + lq * 16);
#pragma unroll
        for (int mm = 0; mm < 8; mm++) {
          int rowd = mm * 16 + lr;
          int phys = (rowd * 128 + kc2 * 64 + lq * 16) ^ ((rowd & 7) << 4);
          half8 av = *(const half8*)((const char*)Vl + phys);
          accO[g][mm] = __builtin_amdgcn_mfma_f32_16x16x32_f16(av, bp, accO[g][mm], 0, 0, 0);
        }
      }
    }
    __syncthreads();
  }
#pragma unroll
  for (int g = 0; g < 2; g++) {
    float rinv = 1.f / lrun[g];
    int qrow = g ? qrow1 : qrow0;
#pragma unroll
    for (int mm = 0; mm < 8; mm++) {
      ushort4 pk;
      pk.x = f2bf(accO[g][mm][0] * rinv); pk.y = f2bf(accO[g][mm][1] * rinv);
      pk.z = f2bf(accO[g][mm][2] * rinv); pk.w = f2bf(accO[g][mm][3] * rinv);
      *(ushort4*)&out[(size_t)qrow * 4096 + hd * 128 + mm * 16 + lq * 4] = pk;
    }
  }
}

// ---------- launch ----------
extern "C" void kernel_launch(void* const* d_in, const int* in_sizes, int n_in,
                              void* d_out, int out_size, void* d_ws, size_t ws_size,
                              hipStream_t stream) {
  const float* x      = (const float*)d_in[0];
  const float* wq     = (const float*)d_in[1];
  const float* wk     = (const float*)d_in[2];
  const float* wv     = (const float*)d_in[3];
  const float* wo     = (const float*)d_in[4];
  const float* w1     = (const float*)d_in[5];
  const float* w2     = (const float*)d_in[6];
  const float* w3     = (const float*)d_in[7];
  const float* g_attn = (const float*)d_in[8];
  const float* g_ffn  = (const float*)d_in[9];

  char* ws = (char*)d_ws;
  char* R0 = ws;                                   // 180.4MB rotating weights
  char* R1 = R0 + (size_t)22016 * 4096 * 2;        // 67.1MB xo,h2
  char* R2 = R1 + (size_t)8192 * 4096 * 2;         // 33.6MB h_hi,h_lo; later x1silu (w/ R3)
  char* R3 = R2 + (size_t)2 * 2048 * 4096 * 2;     // 33.6MB qk fp16
  char* R4 = R3 + (size_t)2048 * 8192 * 2;         // 33.6MB ao, vT
  char* RT = R4 + (size_t)2 * 2048 * 4096 * 2;     // 1MB rope table
  (void)ws_size; (void)in_sizes; (void)n_in; (void)out_size;

  u16* wA     = (u16*)R0;
  u16* h_hi   = (u16*)R2;                           // fp16
  u16* h_lo   = (u16*)(R2 + (size_t)2048 * 4096 * 2);
  u16* qk     = (u16*)R3;                           // fp16 [2048][8192]: q | k
  u16* ao     = (u16*)R4;                           // bf16
  u16* vT     = (u16*)(R4 + (size_t)2048 * 4096 * 2);  // fp16 [d][s]
  float* xo   = (float*)R1;
  u16* h2     = (u16*)(R1 + (size_t)2048 * 4096 * 4);  // bf16
  u16* x1silu = (u16*)R2;                           // h/qk dead after attn; spans R2+R3
  float* tab  = (float*)RT;

  dim3 tb(32, 8);

  rope_table_kernel<<<512, 256, 0, stream>>>(tab);
  rmsnorm_kernel<true><<<2048, 256, 0, stream>>>(x, g_attn, h_hi, h_lo);
  // fused Q|K projection: fp16 2-term split, K'=8192, fp16 out
  tconv_kernel<true><<<dim3(64, 64), tb, 0, stream>>>(wq, wA, 4096, 4096);
  tconv_kernel<true><<<dim3(64, 64), tb, 0, stream>>>(wk, wA + (size_t)4096 * 4096, 4096, 4096);
  gemm8_kernel<4, true, 1><<<dim3(32, 8), 512, 0, stream>>>(
      h_hi, h_lo, wA, qk, 2048, 8192, 8192, 4096, 4096);
  rope_inplace_kernel<<<32768, 256, 0, stream>>>(qk, tab);
  // V projection (fp16) with fused transpose: writes fp16 vT [d][s]
  tconv_kernel<true><<<dim3(64, 64), tb, 0, stream>>>(wv, wA, 4096, 4096);
  gemm8n_kernel<2, 1><<<dim3(16, 16), 512, 0, stream>>>(h_hi, wA, vT, 2048, 4096, 4096, 4096, 4096);
  // attention (fp16 q/k/v/p; QBLK=128 via 4 waves x 2 q-groups)
  attn_kernel<<<dim3(16, 32), 256, 0, stream>>>(qk, qk + 4096, vT, ao);
  // xo = ao @ wo (bf16 GEMM, f32 out)
  tconv_kernel<false><<<dim3(64, 64), tb, 0, stream>>>(wo, wA, 4096, 4096);
  gemm8n_kernel<0, 0><<<dim3(16, 16), 512, 0, stream>>>(ao, wA, xo, 2048, 4096, 4096, 4096, 4096);
  rmsnorm_kernel<false><<<2048, 256, 0, stream>>>(xo, g_ffn, h2, nullptr);
  // FFN up with fused silu on the 256^2 8-phase structure (bf16)
  tconv_ilv_kernel<<<dim3(172, 64), tb, 0, stream>>>(w1, wA, 4096, 11008, 0);
  tconv_ilv_kernel<<<dim3(172, 64), tb, 0, stream>>>(w3, wA, 4096, 11008, 128);
  gemm8_kernel<3, false, 0><<<dim3(86, 8), 512, 0, stream>>>(
      h2, nullptr, wA, x1silu, 2048, 11008, 4096, 4096, 4096);
  // out = x1silu @ w2 : K=11008
  tconv_kernel<false><<<dim3(64, 172), tb, 0, stream>>>(w2, wA, 11008, 4096);
  gemm8n_kernel<0, 0><<<dim3(16, 16), 512, 0, stream>>>(x1silu, wA, (float*)d_out, 2048, 4096, 11008, 11008, 11008);
}

// Round 18
// 1365.674 us; speedup vs baseline: 1.2265x; 1.0752x over previous
//
#include <hip/hip_runtime.h>
#include <math.h>

// ---------- types / helpers ----------
typedef unsigned short u16;
typedef short short8 __attribute__((ext_vector_type(8)));
typedef _Float16 half8 __attribute__((ext_vector_type(8)));
typedef float f32x4 __attribute__((ext_vector_type(4)));

#define DEV static __device__ __forceinline__

DEV float bf2f(u16 h) { union { unsigned int u; float f; } v; v.u = ((unsigned int)h) << 16; return v.f; }
DEV u16 f2bf(float f) {
  union { float f; unsigned int u; } v; v.f = f;
  unsigned int r = v.u + 0x7FFFu + ((v.u >> 16) & 1u);  // RNE
  return (u16)(r >> 16);
}
DEV u16 f2h(float f) { union { _Float16 h; u16 u; } v; v.h = (_Float16)f; return v.u; }
DEV float h2f(u16 b) { union { u16 u; _Float16 h; } v; v.u = b; return (float)v.h; }

DEV void gl_lds16(const void* g, void* l) {
  __builtin_amdgcn_global_load_lds(
      (const __attribute__((address_space(1))) unsigned int*)g,
      (__attribute__((address_space(3))) unsigned int*)l, 16, 0, 0);
}

template <int N> DEV void vm_wait() {
  if constexpr (N == 0) asm volatile("s_waitcnt vmcnt(0)" ::: "memory");
  else if constexpr (N == 6) asm volatile("s_waitcnt vmcnt(6)" ::: "memory");
  else if constexpr (N == 8) asm volatile("s_waitcnt vmcnt(8)" ::: "memory");
  else static_assert(N == 0 || N == 6 || N == 8, "add literal");
}

DEV void lgkm0_pin() {
  asm volatile("s_waitcnt lgkmcnt(0)" ::: "memory");
  __builtin_amdgcn_sched_barrier(0);
}

// generic MFMA over bf16 (DT=0) or fp16 (DT=1) fragments held in short8
template <int DT>
DEV f32x4 mm_frag(short8 a, short8 b, f32x4 c) {
  if constexpr (DT == 0)
    return __builtin_amdgcn_mfma_f32_16x16x32_bf16(a, b, c, 0, 0, 0);
  else
    return __builtin_amdgcn_mfma_f32_16x16x32_f16(*(half8*)&a, *(half8*)&b, c, 0, 0, 0);
}

// XCD-aware block swizzle (bijective; all grids have nwg%8==0).
DEV void xcd_swizzle(int& bx, int& by) {
  int gx = gridDim.x, gy = gridDim.y;
  int lin = by * gx + bx;
  int xcd = lin & 7, i = lin >> 3;
  if ((gx & 7) == 0) {
    int cx = gx >> 3;
    bx = xcd * cx + i % cx;
    by = i / cx;
  } else {
    int cpx = (gx * gy) >> 3;
    int swz = xcd * cpx + i;
    bx = swz % gx;
    by = swz / gx;
  }
}

// ---------- RMSNorm: f32 [2048][4096] -> fp16 (F16=1) or bf16 ----------
template <bool F16>
__global__ __launch_bounds__(256) void rmsnorm_kernel(
    const float* __restrict__ x, const float* __restrict__ g, u16* __restrict__ oh) {
  int row = blockIdx.x, t = threadIdx.x;
  const float* xr = x + (size_t)row * 4096;
  float4 vals[4];
  float s = 0.f;
#pragma unroll
  for (int i = 0; i < 4; i++) {
    vals[i] = ((const float4*)xr)[t + i * 256];
    s += vals[i].x * vals[i].x + vals[i].y * vals[i].y + vals[i].z * vals[i].z + vals[i].w * vals[i].w;
  }
#pragma unroll
  for (int m = 1; m < 64; m <<= 1) s += __shfl_xor(s, m);
  __shared__ float red[4];
  if ((t & 63) == 0) red[t >> 6] = s;
  __syncthreads();
  s = red[0] + red[1] + red[2] + red[3];
  float rinv = rsqrtf(s * (1.f / 4096.f) + 1.1920929e-07f);
#pragma unroll
  for (int i = 0; i < 4; i++) {
    float4 gv = ((const float4*)g)[t + i * 256];
    float4 v = vals[i];
    float f[4] = {v.x * rinv * gv.x, v.y * rinv * gv.y, v.z * rinv * gv.z, v.w * rinv * gv.w};
    ushort4 rh;
    u16* hp = (u16*)&rh;
#pragma unroll
    for (int j = 0; j < 4; j++) hp[j] = F16 ? f2h(f[j]) : f2bf(f[j]);
    ((ushort4*)(oh + (size_t)row * 4096))[t + i * 256] = rh;
  }
}

// ---------- transpose-convert, 64x64 tiles: w f32 [K][N] -> wT (bf16|fp16) [N][K] ----------
template <bool F16>
__global__ void tconv_kernel(const float* __restrict__ in, u16* __restrict__ out, int K, int N) {
  __shared__ float tile[64][65];
  int k0 = blockIdx.y * 64, n0 = blockIdx.x * 64;
  int tx = threadIdx.x, ty = threadIdx.y;
#pragma unroll
  for (int i = 0; i < 8; i++) {
    int r = ty + 8 * i;
    float2 v = *(const float2*)&in[(size_t)(k0 + r) * N + n0 + tx * 2];
    tile[r][tx * 2] = v.x;
    tile[r][tx * 2 + 1] = v.y;
  }
  __syncthreads();
#pragma unroll
  for (int i = 0; i < 8; i++) {
    int c = ty + 8 * i;
    ushort2 o;
    o.x = F16 ? f2h(tile[tx * 2][c]) : f2bf(tile[tx * 2][c]);
    o.y = F16 ? f2h(tile[tx * 2 + 1][c]) : f2bf(tile[tx * 2 + 1][c]);
    *(ushort2*)&out[(size_t)(n0 + c) * K + k0 + tx * 2] = o;
  }
}

// ---------- 64x64 transpose-convert, 128-col interleave (for [w1|w3] packing) ----------
template <bool F16>
__global__ void tconv_ilv_kernel(const float* __restrict__ in, u16* __restrict__ out,
                                 int K, int N, int off) {
  __shared__ float tile[64][65];
  int k0 = blockIdx.y * 64, n0 = blockIdx.x * 64;
  int tx = threadIdx.x, ty = threadIdx.y;
#pragma unroll
  for (int i = 0; i < 8; i++) {
    int r = ty + 8 * i;
    float2 v = *(const float2*)&in[(size_t)(k0 + r) * N + n0 + tx * 2];
    tile[r][tx * 2] = v.x;
    tile[r][tx * 2 + 1] = v.y;
  }
  __syncthreads();
#pragma unroll
  for (int i = 0; i < 8; i++) {
    int c = ty + 8 * i;
    int n = n0 + c;
    int orow = ((n >> 7) << 8) + (n & 127) + off;
    ushort2 o;
    o.x = F16 ? f2h(tile[tx * 2][c]) : f2bf(tile[tx * 2][c]);
    o.y = F16 ? f2h(tile[tx * 2 + 1][c]) : f2bf(tile[tx * 2 + 1][c]);
    *(ushort2*)&out[(size_t)orow * K + k0 + tx * 2] = o;
  }
}

// ---------- RoPE cos/sin table (double precision): tab[s][j] = {cos,sin} ----------
__global__ __launch_bounds__(256) void rope_table_kernel(float* __restrict__ tab) {
  int i = blockIdx.x * 256 + threadIdx.x;  // 2048*64
  int j = i & 63, s = i >> 6;
  double freq = pow(10000.0, -(double)j / 64.0);
  double ang = (double)s * freq;
  tab[i * 2] = (float)cos(ang);
  tab[i * 2 + 1] = (float)sin(ang);
}

// ---------- RoPE in place on fp16 [2048][8192]; one wave owns one 128-col slot ----------
__global__ __launch_bounds__(256) void rope_inplace_kernel(
    u16* q, const float* __restrict__ tab) {
  int idx = blockIdx.x * 256 + threadIdx.x;  // (s, slot6, j)
  int j = idx & 63, hd = (idx >> 6) & 63, s = idx >> 12;
  size_t base = (size_t)s * 8192 + hd * 128;
  float xe = h2f(q[base + 2 * j]);
  float xo = h2f(q[base + 2 * j + 1]);
  float cs = tab[(s * 64 + j) * 2], sn = tab[(s * 64 + j) * 2 + 1];
  q[base + j] = f2h(xe * cs - xo * sn);
  q[base + 64 + j] = f2h(xe * sn + xo * cs);
}

// ---------- 8-phase 256x256 GEMM, 2-tiles-ahead staging (round-5 proven) ----------
// DT: MFMA input dtype (0=bf16, 1=fp16).
// OUT: 0=f32, 1=bf16, 3=fused silu (interleaved [w1|w3]; dtype per DT), 4=fp16.
template <int OUT, int DT>
__global__ __launch_bounds__(512, 2) void gemm8_kernel(
    const u16* __restrict__ A, const u16* __restrict__ B, void* __restrict__ C,
    int M, int N, int K, int lda, int ldb) {
  __shared__ __attribute__((aligned(16))) u16 SMEM[65536];  // 128KB: A 64KB | B 64KB
  int t = threadIdx.x, l = t & 63, w = t >> 6;
  int bx = blockIdx.x, by = blockIdx.y;
  xcd_swizzle(bx, by);
  int m0 = by * 256, n0 = bx * 256;
  int wm = w >> 2, wn = w & 3, bh = wn >> 1;
  f32x4 acc[8][4] = {};
  int nk = K >> 6;

  auto AsP = [&](int d, int h) -> u16* { return SMEM + (d * 2 + h) * 8192; };
  auto BsP = [&](int d, int h) -> u16* { return SMEM + 32768 + (d * 2 + h) * 8192; };

  auto stageA = [&](int kt, int dd) {
    int kc = kt << 6;
#pragma unroll
    for (int i = 0; i < 4; i++) {
      int id = i * 512 + t;
      int hh = id >> 10, idc = id & 1023;
      int r = idc >> 3, cb = idc & 7;
      int csw = ((cb * 16) ^ ((r & 7) << 4)) >> 1;
      gl_lds16(&A[(size_t)(m0 + hh * 128 + r) * lda + kc + csw], AsP(dd, hh) + idc * 8);
    }
  };
  auto stageB = [&](int kt, int dd) {
    int kc = kt << 6;
#pragma unroll
    for (int i = 0; i < 4; i++) {
      int id = i * 512 + t;
      int hh = id >> 10, idc = id & 1023;
      int r = idc >> 3, cb = idc & 7;
      int csw = ((cb * 16) ^ ((r & 7) << 4)) >> 1;
      gl_lds16(&B[(size_t)(n0 + hh * 128 + r) * ldb + kc + csw], BsP(dd, hh) + idc * 8);
    }
  };

  int lq = l >> 4, lr = l & 15;
  short8 af[4][2], bf[4][2];
  auto rdA = [&](int d, int mh) {
    const char* Ax = (const char*)AsP(d, wm);
#pragma unroll
    for (int m = 0; m < 4; m++) {
      int r = mh * 64 + m * 16 + lr;
      int rb = r * 128, rx = (r & 7) << 4;
#pragma unroll
      for (int kh = 0; kh < 2; kh++)
        af[m][kh] = *(const short8*)(Ax + rb + ((kh * 64 + lq * 16) ^ rx));
    }
  };
  auto rdB2 = [&](int d, int nlo, int nhi) {
    const char* Bx = (const char*)BsP(d, bh);
#pragma unroll
    for (int n = 0; n < 4; n++) {
      if (n < nlo || n >= nhi) continue;
      int r = (wn & 1) * 64 + n * 16 + lr;
      int rb = r * 128, rx = (r & 7) << 4;
#pragma unroll
      for (int kh = 0; kh < 2; kh++)
        bf[n][kh] = *(const short8*)(Bx + rb + ((kh * 64 + lq * 16) ^ rx));
    }
  };
  auto mm8 = [&](int mo, int no) {
    __builtin_amdgcn_s_setprio(1);
#pragma unroll
    for (int m = 0; m < 4; m++)
#pragma unroll
      for (int n = 0; n < 2; n++)
#pragma unroll
        for (int kh = 0; kh < 2; kh++)
          acc[mo + m][no + n] = mm_frag<DT>(af[m][kh], bf[no + n][kh], acc[mo + m][no + n]);
    __builtin_amdgcn_s_setprio(0);
  };

  stageB(0, 0); stageA(0, 0);
  stageB(1, 1); stageA(1, 1);
  vm_wait<8>();
  __builtin_amdgcn_s_barrier();

  for (int kt = 0; kt < nk; ++kt) {
    int d = kt & 1;
    rdA(d, 0);
    rdB2(d, 0, 2);
    __builtin_amdgcn_s_barrier();
    lgkm0_pin();
    mm8(0, 0);
    __builtin_amdgcn_s_barrier();
    rdB2(d, 2, 4);
    __builtin_amdgcn_s_barrier();
    lgkm0_pin();
    mm8(0, 2);
    __builtin_amdgcn_s_barrier();
    rdA(d, 1);
    if (kt + 2 < nk) stageB(kt + 2, d);
    __builtin_amdgcn_s_barrier();
    lgkm0_pin();
    mm8(4, 2);
    __builtin_amdgcn_s_barrier();
    if (kt + 2 < nk) stageA(kt + 2, d);
    __builtin_amdgcn_s_barrier();
    mm8(4, 0);
    if (kt + 2 < nk) vm_wait<8>();
    else vm_wait<0>();
    __builtin_amdgcn_s_barrier();
  }

  if (OUT == 3) {
    __syncthreads();
    float* EPI = (float*)SMEM;  // 256 x 128 f32 = 128KB
    if (wn >= 2) {
#pragma unroll
      for (int m = 0; m < 8; m++)
#pragma unroll
        for (int i = 0; i < 4; i++) {
          int rl = wm * 128 + m * 16 + lq * 4 + i;
#pragma unroll
          for (int n = 0; n < 4; n++)
            EPI[rl * 128 + (wn - 2) * 64 + n * 16 + lr] = acc[m][n][i];
        }
    }
    __syncthreads();
    if (wn < 2) {
      u16* Ob = (u16*)C;
      int cb = n0 >> 1;
#pragma unroll
      for (int m = 0; m < 8; m++)
#pragma unroll
        for (int i = 0; i < 4; i++) {
          int rl = wm * 128 + m * 16 + lq * 4 + i;
          int row = m0 + rl;
#pragma unroll
          for (int n = 0; n < 4; n++) {
            float a = acc[m][n][i];
            float b = EPI[rl * 128 + wn * 64 + n * 16 + lr];
            float r = a * (b / (1.f + expf(-b)));
            Ob[(size_t)row * N + cb + wn * 64 + n * 16 + lr] = (DT == 1) ? f2h(r) : f2bf(r);
          }
        }
    }
    return;
  }

#pragma unroll
  for (int m = 0; m < 8; m++) {
#pragma unroll
    for (int i = 0; i < 4; i++) {
      int row = m0 + wm * 128 + m * 16 + lq * 4 + i;
      size_t rb = (size_t)row * N + n0 + wn * 64 + lr;
#pragma unroll
      for (int n = 0; n < 4; n++) {
        float f = acc[m][n][i];
        if (OUT == 0) ((float*)C)[rb + n * 16] = f;
        else if (OUT == 1) ((u16*)C)[rb + n * 16] = f2bf(f);
        else ((u16*)C)[rb + n * 16] = f2h(f);
      }
    }
  }
}

// ---------- 2-phase 128x256 GEMM (round-5 proven; N=4096 shapes) ----------
// OUT: 0=f32, 2=transposed [N][M] (dtype per DT).
template <int OUT, int DT>
__global__ __launch_bounds__(512, 2) void gemm8n_kernel(
    const u16* __restrict__ A, const u16* __restrict__ B, void* __restrict__ C,
    int M, int N, int K, int lda, int ldb) {
  __shared__ __attribute__((aligned(16))) u16 As[2][128 * 64];
  __shared__ __attribute__((aligned(16))) u16 Bs3[3][256 * 64];
  int t = threadIdx.x, l = t & 63, w = t >> 6;
  int bx = blockIdx.x, by = blockIdx.y;
  xcd_swizzle(bx, by);
  int m0 = by * 128, n0 = bx * 256;
  int wm = w >> 2, wn = w & 3;
  f32x4 acc[4][4] = {};
  int nk = K >> 6;

  auto stageA = [&](int kt, int dd) {
    int kc = kt << 6;
#pragma unroll
    for (int i = 0; i < 2; i++) {
      int id = i * 512 + t;
      int r = id >> 3, cb = id & 7;
      int csw = ((cb * 16) ^ ((r & 7) << 4)) >> 1;
      gl_lds16(&A[(size_t)(m0 + r) * lda + kc + csw], &As[dd][id * 8]);
    }
  };
  auto stageB = [&](int kt, int bb) {
    int kc = kt << 6;
#pragma unroll
    for (int i = 0; i < 4; i++) {
      int id = i * 512 + t;
      int r = id >> 3, cb = id & 7;
      int csw = ((cb * 16) ^ ((r & 7) << 4)) >> 1;
      gl_lds16(&B[(size_t)(n0 + r) * ldb + kc + csw], &Bs3[bb][id * 8]);
    }
  };

  int lq = l >> 4, lr = l & 15;
  short8 af0[4], af1[4], bf0[4], bf1[4];
  auto rdA4 = [&](short8 (&dst)[4], int d, int kh) {
    const char* Ax = (const char*)As[d];
#pragma unroll
    for (int m = 0; m < 4; m++) {
      int r = wm * 64 + m * 16 + lr;
      dst[m] = *(const short8*)(Ax + r * 128 + ((kh * 64 + lq * 16) ^ ((r & 7) << 4)));
    }
  };
  auto rdB4 = [&](short8 (&dst)[4], int bb, int kh) {
    const char* Bx = (const char*)Bs3[bb];
#pragma unroll
    for (int n = 0; n < 4; n++) {
      int r = wn * 64 + n * 16 + lr;
      dst[n] = *(const short8*)(Bx + r * 128 + ((kh * 64 + lq * 16) ^ ((r & 7) << 4)));
    }
  };
  auto mm16 = [&](short8 (&a)[4], short8 (&b)[4]) {
    __builtin_amdgcn_s_setprio(1);
#pragma unroll
    for (int m = 0; m < 4; m++)
#pragma unroll
      for (int n = 0; n < 4; n++)
        acc[m][n] = mm_frag<DT>(a[m], b[n], acc[m][n]);
    __builtin_amdgcn_s_setprio(0);
  };

  stageB(0, 0); stageA(0, 0);
  stageB(1, 1); stageA(1, 1);
  vm_wait<6>();
  __builtin_amdgcn_s_barrier();

  for (int kt = 0; kt < nk; ++kt) {
    int d = kt & 1;
    int bb = kt % 3, bb2 = (kt + 2) % 3;
    if (kt + 2 < nk) stageB(kt + 2, bb2);
    rdA4(af0, d, 0); rdB4(bf0, bb, 0);
    __builtin_amdgcn_s_barrier();
    lgkm0_pin();
    mm16(af0, bf0);
    __builtin_amdgcn_s_barrier();
    rdA4(af1, d, 1); rdB4(bf1, bb, 1);
    lgkm0_pin();
    __builtin_amdgcn_s_barrier();
    if (kt + 2 < nk) { stageA(kt + 2, d); vm_wait<6>(); }
    else vm_wait<0>();
    mm16(af1, bf1);
    __builtin_amdgcn_s_barrier();
  }
  if (OUT == 2) {
    u16* Cb = (u16*)C;
#pragma unroll
    for (int m = 0; m < 4; m++) {
      int sbase = m0 + wm * 64 + m * 16 + lq * 4;
#pragma unroll
      for (int n = 0; n < 4; n++) {
        int dg = n0 + wn * 64 + n * 16 + lr;
        ushort4 pk;
        if (DT == 1) {
          pk.x = f2h(acc[m][n][0]); pk.y = f2h(acc[m][n][1]);
          pk.z = f2h(acc[m][n][2]); pk.w = f2h(acc[m][n][3]);
        } else {
          pk.x = f2bf(acc[m][n][0]); pk.y = f2bf(acc[m][n][1]);
          pk.z = f2bf(acc[m][n][2]); pk.w = f2bf(acc[m][n][3]);
        }
        *(ushort4*)&Cb[(size_t)dg * M + sbase] = pk;
      }
    }
    return;
  }
#pragma unroll
  for (int m = 0; m < 4; m++) {
#pragma unroll
    for (int i = 0; i < 4; i++) {
      int row = m0 + wm * 64 + m * 16 + lq * 4 + i;
      size_t rb = (size_t)row * N + n0 + wn * 64 + lr;
#pragma unroll
      for (int n = 0; n < 4; n++)
        ((float*)C)[rb + n * 16] = acc[m][n][i];
    }
  }
}

// ---------- flash attention (no scale, no mask), full fp16; fp16 out ----------
// QBLK=128 via 4 waves x 2 q-groups (r15/r16 proven structure).
__global__ __launch_bounds__(256, 2) void attn_kernel(
    const u16* __restrict__ qf16, const u16* __restrict__ kf16,
    const u16* __restrict__ vt, u16* __restrict__ out) {
  const int QS = 8192;
  __shared__ __attribute__((aligned(16))) u16 KH[64 * 128];   // fp16 [kv][d], XOR-swizzled
  __shared__ __attribute__((aligned(16))) u16 Vl[128 * 64];   // fp16 [d][kv], XOR-swizzled
  __shared__ __attribute__((aligned(16))) u16 Pl[8][16 * 72]; // fp16 per (wave,group) [q][kv]
  int t = threadIdx.x, l = t & 63, w = t >> 6;
  int hd = blockIdx.y, q0 = blockIdx.x * 128;
  int lr = l & 15, lq = l >> 4;
  int qrow0 = q0 + (w * 2) * 16 + lr;
  int qrow1 = q0 + (w * 2 + 1) * 16 + lr;
  half8 qf[2][4];
#pragma unroll
  for (int g = 0; g < 2; g++) {
    size_t qoff = (size_t)(g ? qrow1 : qrow0) * QS + hd * 128 + lq * 8;
#pragma unroll
    for (int kc = 0; kc < 4; kc++)
      qf[g][kc] = *(const half8*)&qf16[qoff + kc * 32];
  }
  f32x4 accO[2][8] = {};
  float mrun[2] = {-__builtin_inff(), -__builtin_inff()};
  float lrun[2] = {0.f, 0.f};
  for (int kv0 = 0; kv0 < 2048; kv0 += 64) {
#pragma unroll
    for (int i = 0; i < 4; i++) {
      int ci = i * 256 + t;
      int row = ci >> 4;
      int cb = (ci & 15) ^ (row & 7);
      gl_lds16(&kf16[(size_t)(kv0 + row) * QS + hd * 128 + cb * 8], &KH[ci * 8]);
    }
#pragma unroll
    for (int i = 0; i < 4; i++) {
      int ci = i * 256 + t;
      int row = ci >> 3;
      int cb = (ci & 7) ^ (row & 7);
      gl_lds16(&vt[((size_t)hd * 128 + row) * 2048 + kv0 + cb * 8], &Vl[ci * 8]);
    }
    __syncthreads();
#pragma unroll
    for (int g = 0; g < 2; g++) {
      f32x4 accS[4];
#pragma unroll
      for (int mm = 0; mm < 4; mm++) {
        accS[mm] = (f32x4){0.f, 0.f, 0.f, 0.f};
#pragma unroll
        for (int kc = 0; kc < 4; kc++) {
          int rowk = mm * 16 + lr;
          int phys = (rowk * 256 + kc * 64 + lq * 16) ^ ((rowk & 7) << 4);
          half8 a_h = *(const half8*)((const char*)KH + phys);
          accS[mm] = __builtin_amdgcn_mfma_f32_16x16x32_f16(a_h, qf[g][kc], accS[mm], 0, 0, 0);
        }
      }
      float tmax = -__builtin_inff();
#pragma unroll
      for (int mm = 0; mm < 4; mm++)
        tmax = fmaxf(tmax, fmaxf(fmaxf(accS[mm][0], accS[mm][1]), fmaxf(accS[mm][2], accS[mm][3])));
      tmax = fmaxf(tmax, __shfl_xor(tmax, 16));
      tmax = fmaxf(tmax, __shfl_xor(tmax, 32));
      float mnew = fmaxf(mrun[g], tmax);
      float scale = expf(mrun[g] - mnew);
      float psum = 0.f;
      u16* Pw = &Pl[w * 2 + g][0];
#pragma unroll
      for (int mm = 0; mm < 4; mm++) {
        float p0 = expf(accS[mm][0] - mnew), p1 = expf(accS[mm][1] - mnew);
        float p2 = expf(accS[mm][2] - mnew), p3 = expf(accS[mm][3] - mnew);
        psum += (p0 + p1) + (p2 + p3);
        ushort4 pk;
        pk.x = f2h(p0); pk.y = f2h(p1); pk.z = f2h(p2); pk.w = f2h(p3);
        *(ushort4*)&Pw[lr * 72 + mm * 16 + lq * 4] = pk;
      }
      psum += __shfl_xor(psum, 16);
      psum += __shfl_xor(psum, 32);
      lrun[g] = lrun[g] * scale + psum;
      mrun[g] = mnew;
#pragma unroll
      for (int mm = 0; mm < 8; mm++) accO[g][mm] = accO[g][mm] * scale;
#pragma unroll
      for (int kc2 = 0; kc2 < 2; kc2++) {
        half8 bp = *(const half8*)((const char*)Pw + lr * 144 + kc2 * 64 + lq * 16);
#pragma unroll
        for (int mm = 0; mm < 8; mm++) {
          int rowd = mm * 16 + lr;
          int phys = (rowd * 128 + kc2 * 64 + lq * 16) ^ ((rowd & 7) << 4);
          half8 av = *(const half8*)((const char*)Vl + phys);
          accO[g][mm] = __builtin_amdgcn_mfma_f32_16x16x32_f16(av, bp, accO[g][mm], 0, 0, 0);
        }
      }
    }
    __syncthreads();
  }
#pragma unroll
  for (int g = 0; g < 2; g++) {
    float rinv = 1.f / lrun[g];
    int qrow = g ? qrow1 : qrow0;
#pragma unroll
    for (int mm = 0; mm < 8; mm++) {
      ushort4 pk;
      pk.x = f2h(accO[g][mm][0] * rinv); pk.y = f2h(accO[g][mm][1] * rinv);
      pk.z = f2h(accO[g][mm][2] * rinv); pk.w = f2h(accO[g][mm][3] * rinv);
      *(ushort4*)&out[(size_t)qrow * 4096 + hd * 128 + mm * 16 + lq * 4] = pk;
    }
  }
}

// ---------- launch ----------
extern "C" void kernel_launch(void* const* d_in, const int* in_sizes, int n_in,
                              void* d_out, int out_size, void* d_ws, size_t ws_size,
                              hipStream_t stream) {
  const float* x      = (const float*)d_in[0];
  const float* wq     = (const float*)d_in[1];
  const float* wk     = (const float*)d_in[2];
  const float* wv     = (const float*)d_in[3];
  const float* wo     = (const float*)d_in[4];
  const float* w1     = (const float*)d_in[5];
  const float* w2     = (const float*)d_in[6];
  const float* w3     = (const float*)d_in[7];
  const float* g_attn = (const float*)d_in[8];
  const float* g_ffn  = (const float*)d_in[9];

  char* ws = (char*)d_ws;
  char* R0 = ws;                                   // 180.4MB rotating weights (fp16)
  char* R1 = R0 + (size_t)22016 * 4096 * 2;        // 67.1MB xo,h2
  char* R2 = R1 + (size_t)8192 * 4096 * 2;         // 16.8MB h; later x1silu (w/ R3)
  char* R3 = R2 + (size_t)2048 * 4096 * 2;         // 33.6MB qk fp16
  char* R4 = R3 + (size_t)2048 * 8192 * 2;         // 33.6MB ao, vT
  char* RT = R4 + (size_t)2 * 2048 * 4096 * 2;     // 1MB rope table
  (void)ws_size; (void)in_sizes; (void)n_in; (void)out_size;

  u16* wA     = (u16*)R0;
  u16* h      = (u16*)R2;                           // fp16
  u16* qk     = (u16*)R3;                           // fp16 [2048][8192]: q | k
  u16* ao     = (u16*)R4;                           // fp16
  u16* vT     = (u16*)(R4 + (size_t)2048 * 4096 * 2);  // fp16 [d][s]
  float* xo   = (float*)R1;
  u16* h2     = (u16*)(R1 + (size_t)2048 * 4096 * 4);  // fp16
  u16* x1silu = (u16*)R2;                           // fp16; h/qk dead after attn; spans R2+R3
  float* tab  = (float*)RT;

  dim3 tb(32, 8);

  rope_table_kernel<<<512, 256, 0, stream>>>(tab);
  rmsnorm_kernel<true><<<2048, 256, 0, stream>>>(x, g_attn, h);
  // fused Q|K projection: single-product fp16 GEMM, K=4096, fp16 out
  tconv_kernel<true><<<dim3(64, 64), tb, 0, stream>>>(wq, wA, 4096, 4096);
  tconv_kernel<true><<<dim3(64, 64), tb, 0, stream>>>(wk, wA + (size_t)4096 * 4096, 4096, 4096);
  gemm8_kernel<4, 1><<<dim3(32, 8), 512, 0, stream>>>(
      h, wA, qk, 2048, 8192, 4096, 4096, 4096);
  rope_inplace_kernel<<<32768, 256, 0, stream>>>(qk, tab);
  // V projection (fp16) with fused transpose: writes fp16 vT [d][s]
  tconv_kernel<true><<<dim3(64, 64), tb, 0, stream>>>(wv, wA, 4096, 4096);
  gemm8n_kernel<2, 1><<<dim3(16, 16), 512, 0, stream>>>(h, wA, vT, 2048, 4096, 4096, 4096, 4096);
  // attention (fp16 everywhere; QBLK=128 via 4 waves x 2 q-groups); fp16 ao
  attn_kernel<<<dim3(16, 32), 256, 0, stream>>>(qk, qk + 4096, vT, ao);
  // xo = ao @ wo (fp16 GEMM, f32 out)
  tconv_kernel<true><<<dim3(64, 64), tb, 0, stream>>>(wo, wA, 4096, 4096);
  gemm8n_kernel<0, 1><<<dim3(16, 16), 512, 0, stream>>>(ao, wA, xo, 2048, 4096, 4096, 4096, 4096);
  rmsnorm_kernel<true><<<2048, 256, 0, stream>>>(xo, g_ffn, h2);
  // FFN up with fused silu (fp16) on the 256^2 8-phase structure
  tconv_ilv_kernel<true><<<dim3(172, 64), tb, 0, stream>>>(w1, wA, 4096, 11008, 0);
  tconv_ilv_kernel<true><<<dim3(172, 64), tb, 0, stream>>>(w3, wA, 4096, 11008, 128);
  gemm8_kernel<3, 1><<<dim3(86, 8), 512, 0, stream>>>(
      h2, wA, x1silu, 2048, 11008, 4096, 4096, 4096);
  // out = x1silu @ w2 : K=11008 (fp16 GEMM, f32 out)
  tconv_kernel<true><<<dim3(64, 172), tb, 0, stream>>>(w2, wA, 11008, 4096);
  gemm8n_kernel<0, 1><<<dim3(16, 16), 512, 0, stream>>>(x1silu, wA, (float*)d_out, 2048, 4096, 11008, 11008, 11008);
}